// Round 1
// baseline (1088.347 us; speedup 1.0000x reference)
//
#include <hip/hip_runtime.h>
#include <hip/hip_bf16.h>
#include <stdint.h>

#define DIN 128
#define DOUT 32

typedef unsigned int uint;

__device__ __forceinline__ float frelu(float x) { return x > 0.f ? x : 0.f; }

// ---------------- K1: zero counts + stat accumulators ----------------
__global__ void k_zero(uint* __restrict__ cnt, int ncnt, float* __restrict__ stats, int nstats) {
    int i = blockIdx.x * blockDim.x + threadIdx.x;
    if (i < ncnt) cnt[i] = 0u;
    else if (i < ncnt + nstats) stats[i - ncnt] = 0.f;
}

// ---------------- K2: histogram of dst ----------------
__global__ void k_hist(const int* __restrict__ dst, uint* __restrict__ cnt, int E) {
    int e = blockIdx.x * blockDim.x + threadIdx.x;
    if (e < E) atomicAdd(&cnt[dst[e]], 1u);
}

// ---------------- K3: exclusive scan (single block) ----------------
__global__ __launch_bounds__(1024) void k_scan(const uint* __restrict__ cnt,
                                               uint* __restrict__ off,
                                               uint* __restrict__ cur, int N) {
    __shared__ uint ps[1024];
    const int t = threadIdx.x;
    const int chunk = (N + 1023) >> 10;
    const int b = t * chunk;
    const int e = min(b + chunk, N);
    uint s = 0;
    for (int i = b; i < e; ++i) s += cnt[i];
    ps[t] = s;
    __syncthreads();
    for (int ofs = 1; ofs < 1024; ofs <<= 1) {
        uint v = (t >= ofs) ? ps[t - ofs] : 0u;
        __syncthreads();
        ps[t] += v;
        __syncthreads();
    }
    uint run = (t == 0) ? 0u : ps[t - 1];
    for (int i = b; i < e; ++i) {
        uint c = cnt[i];
        off[i] = run;
        cur[i] = run;
        run += c;
    }
    if (t == 1023) off[N] = run;
}

// ---------------- K4: fill CSR edge array ----------------
__global__ void k_fill(const int* __restrict__ src, const int* __restrict__ dst,
                       uint* __restrict__ cur, uint* __restrict__ esrc, int E) {
    int e = blockIdx.x * blockDim.x + threadIdx.x;
    if (e < E) {
        int d = dst[e];
        uint p = atomicAdd(&cur[d], 1u);
        esrc[p] = (uint)src[e];
    }
}

// ---------------- GEMM: Y = A@Brel, Z = A@Broot + bias, optional BN+relu on A load ----------------
// A [N][128] f32. Block: 256 thr, tile 64 rows x 64 cols, 4x4 accs/thread.
template <int WC, bool NORM>
__global__ __launch_bounds__(256) void k_gemm(
    const float* __restrict__ A, const float* __restrict__ Brel,
    const float* __restrict__ Broot, const float* __restrict__ bias,
    const float* __restrict__ mean, const float* __restrict__ inv,
    const float* __restrict__ gamma, const float* __restrict__ beta,
    float* __restrict__ Y, float* __restrict__ Z, int N) {
    __shared__ float4 As4[64 * 32];   // 64 rows x 128 k, k-contiguous f4, XOR swizzled
    __shared__ float4 Bs4[128 * 16];  // 128 k x 64 cols
    const int tid = threadIdx.x;
    const int rowBase = blockIdx.x * 64;
    const int colBase = blockIdx.y * 64;

    // stage A (coalesced 512B per 32 lanes), optional BN+relu
#pragma unroll
    for (int i = 0; i < 8; ++i) {
        int f = tid + 256 * i;
        int row = f >> 5, c4 = f & 31;
        int grow = rowBase + row;
        float4 v = make_float4(0.f, 0.f, 0.f, 0.f);
        if (grow < N) {
            v = *(const float4*)&A[(size_t)grow * DIN + c4 * 4];
            if constexpr (NORM) {
                int k = c4 * 4;
                float4 m = *(const float4*)&mean[k];
                float4 iv = *(const float4*)&inv[k];
                float4 g = *(const float4*)&gamma[k];
                float4 bb = *(const float4*)&beta[k];
                v.x = frelu((v.x - m.x) * iv.x * g.x + bb.x);
                v.y = frelu((v.y - m.y) * iv.y * g.y + bb.y);
                v.z = frelu((v.z - m.z) * iv.z * g.z + bb.z);
                v.w = frelu((v.w - m.w) * iv.w * g.w + bb.w);
            }
        }
        As4[row * 32 + (c4 ^ ((row >> 2) & 7))] = v;
    }
    // stage B: cols [colBase, colBase+64) of [Brel | Broot]
#pragma unroll
    for (int i = 0; i < 8; ++i) {
        int f = tid + 256 * i;
        int k = f >> 4, c4f = f & 15;
        int gcol = colBase + c4f * 4;
        float4 v;
        if (gcol < WC) v = *(const float4*)&Brel[k * WC + gcol];
        else           v = *(const float4*)&Broot[k * WC + (gcol - WC)];
        Bs4[k * 16 + c4f] = v;
    }
    __syncthreads();

    const int rg = tid >> 4;  // 0..15 -> rows rg*4..rg*4+3
    const int cg = tid & 15;  // 0..15 -> cols cg*4..cg*4+3
    float acc[4][4];
#pragma unroll
    for (int r = 0; r < 4; ++r)
#pragma unroll
        for (int c = 0; c < 4; ++c) acc[r][c] = 0.f;

#pragma unroll 4
    for (int k0 = 0; k0 < 128; k0 += 4) {
        const int k4 = k0 >> 2;
        float4 a[4], bk[4];
#pragma unroll
        for (int j = 0; j < 4; ++j) a[j] = As4[(rg * 4 + j) * 32 + (k4 ^ (rg & 7))];
#pragma unroll
        for (int j = 0; j < 4; ++j) bk[j] = Bs4[(k0 + j) * 16 + cg];
#pragma unroll
        for (int r = 0; r < 4; ++r) {
            const float ar[4] = {a[r].x, a[r].y, a[r].z, a[r].w};
#pragma unroll
            for (int kk = 0; kk < 4; ++kk) {
                acc[r][0] += ar[kk] * bk[kk].x;
                acc[r][1] += ar[kk] * bk[kk].y;
                acc[r][2] += ar[kk] * bk[kk].z;
                acc[r][3] += ar[kk] * bk[kk].w;
            }
        }
    }

    const int c0g = colBase + cg * 4;
#pragma unroll
    for (int r = 0; r < 4; ++r) {
        int grow = rowBase + rg * 4 + r;
        if (grow < N) {
            float4 o = make_float4(acc[r][0], acc[r][1], acc[r][2], acc[r][3]);
            if (c0g < WC) {
                *(float4*)&Y[(size_t)grow * WC + c0g] = o;
            } else {
                int cz = c0g - WC;
                float4 bb = *(const float4*)&bias[cz];
                o.x += bb.x; o.y += bb.y; o.z += bb.z; o.w += bb.w;
                *(float4*)&Z[(size_t)grow * WC + cz] = o;
            }
        }
    }
}

// ---------------- Aggregation: h[n] = sum_{e in CSR(n)} y[esrc[e]] + z[n]; col stats ----------------
// h may alias z (same-element read-then-write). NO __restrict__ on z/h.
template <int DIMS, int IT>
__global__ __launch_bounds__(256) void k_agg(
    const float* __restrict__ y, const float* z, float* h,
    const uint* __restrict__ off, const uint* __restrict__ esrc,
    float* __restrict__ gsum, float* __restrict__ gsq, int N) {
    constexpr int TPN = DIMS / 4;   // threads per node (32 or 8)
    constexpr int G = 256 / TPN;    // node groups per block
    const int tid = threadIdx.x;
    const int c4 = tid & (TPN - 1);
    const int g = tid / TPN;
    const int base = blockIdx.x * (G * IT);
    float4 ssum = make_float4(0.f, 0.f, 0.f, 0.f);
    float4 ssq = make_float4(0.f, 0.f, 0.f, 0.f);

    for (int it = 0; it < IT; ++it) {
        const int n = base + it * G + g;
        if (n < N) {
            const uint beg = off[n], end = off[n + 1];
            float4 acc = make_float4(0.f, 0.f, 0.f, 0.f);
            uint e = beg;
            for (; e + 2 <= end; e += 2) {
                const uint s0 = esrc[e], s1 = esrc[e + 1];
                const float4 a0 = *(const float4*)&y[(size_t)s0 * DIMS + c4 * 4];
                const float4 a1 = *(const float4*)&y[(size_t)s1 * DIMS + c4 * 4];
                acc.x += a0.x + a1.x; acc.y += a0.y + a1.y;
                acc.z += a0.z + a1.z; acc.w += a0.w + a1.w;
            }
            if (e < end) {
                const uint s0 = esrc[e];
                const float4 a0 = *(const float4*)&y[(size_t)s0 * DIMS + c4 * 4];
                acc.x += a0.x; acc.y += a0.y; acc.z += a0.z; acc.w += a0.w;
            }
            const float4 zz = *(const float4*)&z[(size_t)n * DIMS + c4 * 4];
            float4 hh = make_float4(acc.x + zz.x, acc.y + zz.y, acc.z + zz.z, acc.w + zz.w);
            *(float4*)&h[(size_t)n * DIMS + c4 * 4] = hh;
            ssum.x += hh.x; ssum.y += hh.y; ssum.z += hh.z; ssum.w += hh.w;
            ssq.x += hh.x * hh.x; ssq.y += hh.y * hh.y;
            ssq.z += hh.z * hh.z; ssq.w += hh.w * hh.w;
        }
    }

    __shared__ float4 rsum[256];
    __shared__ float4 rsq[256];
    rsum[tid] = ssum;
    rsq[tid] = ssq;
    __syncthreads();
    if (g == 0) {
#pragma unroll
        for (int gg = 1; gg < G; ++gg) {
            float4 a = rsum[gg * TPN + c4];
            float4 b = rsq[gg * TPN + c4];
            ssum.x += a.x; ssum.y += a.y; ssum.z += a.z; ssum.w += a.w;
            ssq.x += b.x; ssq.y += b.y; ssq.z += b.z; ssq.w += b.w;
        }
        const int cb = c4 * 4;
        unsafeAtomicAdd(&gsum[cb + 0], ssum.x);
        unsafeAtomicAdd(&gsum[cb + 1], ssum.y);
        unsafeAtomicAdd(&gsum[cb + 2], ssum.z);
        unsafeAtomicAdd(&gsum[cb + 3], ssum.w);
        unsafeAtomicAdd(&gsq[cb + 0], ssq.x);
        unsafeAtomicAdd(&gsq[cb + 1], ssq.y);
        unsafeAtomicAdd(&gsq[cb + 2], ssq.z);
        unsafeAtomicAdd(&gsq[cb + 3], ssq.w);
    }
}

// ---------------- finalize BN stats ----------------
__global__ void k_finalize(const float* __restrict__ gsum, const float* __restrict__ gsq,
                           float* __restrict__ mean, float* __restrict__ inv, int C, float invN) {
    int c = blockIdx.x * blockDim.x + threadIdx.x;
    if (c < C) {
        float m = gsum[c] * invN;
        float v = gsq[c] * invN - m * m;
        mean[c] = m;
        inv[c] = rsqrtf(v + 1e-5f);
    }
}

// ---------------- final BN+relu elementwise ----------------
__global__ void k_out(const float* __restrict__ h2, const float* __restrict__ mean,
                      const float* __restrict__ inv, const float* __restrict__ gamma,
                      const float* __restrict__ beta, float* __restrict__ out, int nf4) {
    int i = blockIdx.x * blockDim.x + threadIdx.x;
    if (i < nf4) {
        int c = (i & 7) * 4;  // 32 cols = 8 float4 per row
        float4 h = ((const float4*)h2)[i];
        float4 m = *(const float4*)&mean[c];
        float4 iv = *(const float4*)&inv[c];
        float4 g = *(const float4*)&gamma[c];
        float4 b = *(const float4*)&beta[c];
        float4 o;
        o.x = frelu((h.x - m.x) * iv.x * g.x + b.x);
        o.y = frelu((h.y - m.y) * iv.y * g.y + b.y);
        o.z = frelu((h.z - m.z) * iv.z * g.z + b.z);
        o.w = frelu((h.w - m.w) * iv.w * g.w + b.w);
        ((float4*)out)[i] = o;
    }
}

extern "C" void kernel_launch(void* const* d_in, const int* in_sizes, int n_in,
                              void* d_out, int out_size, void* d_ws, size_t ws_size,
                              hipStream_t stream) {
    const float* x      = (const float*)d_in[0];
    const int*   eidx   = (const int*)d_in[1];
    const float* Wrel1  = (const float*)d_in[2];
    const float* brel1  = (const float*)d_in[3];
    const float* Wroot1 = (const float*)d_in[4];
    const float* gamma1 = (const float*)d_in[5];
    const float* beta1  = (const float*)d_in[6];
    const float* Wrel2  = (const float*)d_in[7];
    const float* brel2  = (const float*)d_in[8];
    const float* Wroot2 = (const float*)d_in[9];
    const float* gamma2 = (const float*)d_in[10];
    const float* beta2  = (const float*)d_in[11];

    const int N = in_sizes[0] / DIN;
    const int E = in_sizes[1] / 2;
    const int* src = eidx;
    const int* dst = eidx + E;

    // workspace layout (256B aligned blocks)
    char* p = (char*)d_ws;
    auto alloc = [&](size_t bytes) {
        void* r = (void*)p;
        p += (bytes + 255) & ~(size_t)255;
        return r;
    };
    uint*  cnt   = (uint*)alloc((size_t)(N + 1) * 4);
    uint*  off   = (uint*)alloc((size_t)(N + 1) * 4);
    uint*  cur   = (uint*)alloc((size_t)N * 4);
    uint*  esrc  = (uint*)alloc((size_t)E * 4);
    float* y1    = (float*)alloc((size_t)N * DIN * 4);
    float* z1    = (float*)alloc((size_t)N * DIN * 4);   // h1 aliases z1
    float* y2    = (float*)alloc((size_t)N * DOUT * 4);
    float* z2    = (float*)alloc((size_t)N * DOUT * 4);  // h2 aliases z2
    float* stats = (float*)alloc(640 * 4);
    float* s1sum = stats + 0,   *s1sq = stats + 128;
    float* s2sum = stats + 256, *s2sq = stats + 288;
    float* mean1 = stats + 320, *inv1 = stats + 448;
    float* mean2 = stats + 576, *inv2 = stats + 608;

    const float invN = 1.f / (float)N;

    // K1: zero counts + stat sums (320 floats)
    int nz = (N + 1) + 320;
    k_zero<<<(nz + 255) / 256, 256, 0, stream>>>(cnt, N + 1, stats, 320);
    // K2: histogram
    k_hist<<<(E + 255) / 256, 256, 0, stream>>>(dst, cnt, E);
    // K3: scan -> off, cur
    k_scan<<<1, 1024, 0, stream>>>(cnt, off, cur, N);
    // K4: fill CSR
    k_fill<<<(E + 255) / 256, 256, 0, stream>>>(src, dst, cur, esrc, E);
    // K5: GEMM1  y1 = x@Wrel1, z1 = x@Wroot1 + brel1
    {
        dim3 grid((N + 63) / 64, (2 * DIN) / 64);
        k_gemm<DIN, false><<<grid, 256, 0, stream>>>(x, Wrel1, Wroot1, brel1,
                                                     nullptr, nullptr, nullptr, nullptr,
                                                     y1, z1, N);
    }
    // K6: agg1 + stats  (h1 -> z1)
    k_agg<DIN, 8><<<(N + 63) / 64, 256, 0, stream>>>(y1, z1, z1, off, esrc, s1sum, s1sq, N);
    // K7: finalize BN1
    k_finalize<<<1, 128, 0, stream>>>(s1sum, s1sq, mean1, inv1, DIN, invN);
    // K9: GEMM2 with fused BN1+relu on A; y2 = h1n@Wrel2, z2 = h1n@Wroot2 + brel2
    {
        dim3 grid((N + 63) / 64, (2 * DOUT) / 64);
        k_gemm<DOUT, true><<<grid, 256, 0, stream>>>(z1, Wrel2, Wroot2, brel2,
                                                     mean1, inv1, gamma1, beta1,
                                                     y2, z2, N);
    }
    // K10: agg2 + stats (h2 -> z2)
    k_agg<DOUT, 4><<<(N + 127) / 128, 256, 0, stream>>>(y2, z2, z2, off, esrc, s2sum, s2sq, N);
    // K11: finalize BN2
    k_finalize<<<1, 64, 0, stream>>>(s2sum, s2sq, mean2, inv2, DOUT, invN);
    // K12: final BN2+relu -> out
    int nf4 = N * DOUT / 4;
    k_out<<<(nf4 + 255) / 256, 256, 0, stream>>>(z2, mean2, inv2, gamma2, beta2,
                                                 (float*)d_out, nf4);
}

// Round 2
// 644.478 us; speedup vs baseline: 1.6887x; 1.6887x over previous
//
#include <hip/hip_runtime.h>
#include <hip/hip_bf16.h>
#include <stdint.h>

#define DIN 128
#define DOUT 32
#define NREP 32

typedef unsigned int uint;
typedef float vf4 __attribute__((ext_vector_type(4)));

__device__ __forceinline__ float frelu(float x) { return x > 0.f ? x : 0.f; }

// ---------------- K1: zero counts + stat accumulators ----------------
__global__ void k_zero(uint* __restrict__ cnt, int ncnt, float* __restrict__ stats, int nstats) {
    int i = blockIdx.x * blockDim.x + threadIdx.x;
    if (i < ncnt) cnt[i] = 0u;
    else if (i < ncnt + nstats) stats[i - ncnt] = 0.f;
}

// ---------------- K2: histogram of dst ----------------
__global__ void k_hist(const int* __restrict__ dst, uint* __restrict__ cnt, int E) {
    int e = blockIdx.x * blockDim.x + threadIdx.x;
    if (e < E) atomicAdd(&cnt[dst[e]], 1u);
}

// ---------------- K3a: per-block (1024-elem) sums ----------------
__global__ __launch_bounds__(256) void k_scan_part(const uint* __restrict__ cnt,
                                                   uint* __restrict__ bsum, int N) {
    __shared__ uint red[256];
    const int t = threadIdx.x;
    const int base = blockIdx.x * 1024 + t * 4;
    uint s = 0;
    if (base + 3 < N) {
        uint4 v = *(const uint4*)&cnt[base];
        s = v.x + v.y + v.z + v.w;
    } else {
        for (int i = 0; i < 4; ++i)
            if (base + i < N) s += cnt[base + i];
    }
    red[t] = s;
    __syncthreads();
    for (int ofs = 128; ofs > 0; ofs >>= 1) {
        if (t < ofs) red[t] += red[t + ofs];
        __syncthreads();
    }
    if (t == 0) bsum[blockIdx.x] = red[0];
}

// ---------------- K3b: exclusive scan of block sums (nb <= 256) ----------------
__global__ __launch_bounds__(256) void k_scan_top(uint* __restrict__ bsum, uint* __restrict__ off,
                                                  int nb, int N, int E) {
    __shared__ uint ps[256];
    const int t = threadIdx.x;
    uint v = (t < nb) ? bsum[t] : 0u;
    ps[t] = v;
    __syncthreads();
    for (int ofs = 1; ofs < 256; ofs <<= 1) {
        uint u = (t >= ofs) ? ps[t - ofs] : 0u;
        __syncthreads();
        ps[t] += u;
        __syncthreads();
    }
    if (t < nb) bsum[t] = ps[t] - v;  // exclusive
    if (t == 0) off[N] = (uint)E;
}

// ---------------- K3c: block-local exclusive scan + base -> off, cur ----------------
__global__ __launch_bounds__(256) void k_scan_fill(const uint* __restrict__ cnt,
                                                   const uint* __restrict__ bsum,
                                                   uint* __restrict__ off, uint* __restrict__ cur,
                                                   int N) {
    __shared__ uint ps[256];
    const int t = threadIdx.x;
    const int base = blockIdx.x * 1024 + t * 4;
    uint v[4];
    uint s = 0;
#pragma unroll
    for (int i = 0; i < 4; ++i) {
        uint c = (base + i < N) ? cnt[base + i] : 0u;
        v[i] = s;
        s += c;
    }
    ps[t] = s;
    __syncthreads();
    for (int ofs = 1; ofs < 256; ofs <<= 1) {
        uint u = (t >= ofs) ? ps[t - ofs] : 0u;
        __syncthreads();
        ps[t] += u;
        __syncthreads();
    }
    const uint tp = ps[t] - s + bsum[blockIdx.x];
#pragma unroll
    for (int i = 0; i < 4; ++i) {
        int idx = base + i;
        if (idx < N) {
            uint o = tp + v[i];
            off[idx] = o;
            cur[idx] = o;
        }
    }
}

// ---------------- K4: fill CSR edge array ----------------
__global__ void k_fill(const int* __restrict__ src, const int* __restrict__ dst,
                       uint* __restrict__ cur, uint* __restrict__ esrc, int E) {
    int e = blockIdx.x * blockDim.x + threadIdx.x;
    if (e < E) {
        int d = dst[e];
        uint p = atomicAdd(&cur[d], 1u);
        esrc[p] = (uint)src[e];
    }
}

// ---------------- GEMM: Y = A@Brel, Z = A@Broot + bias, optional BN+relu on A load ----------------
template <int WC, bool NORM>
__global__ __launch_bounds__(256) void k_gemm(
    const float* __restrict__ A, const float* __restrict__ Brel,
    const float* __restrict__ Broot, const float* __restrict__ bias,
    const float* __restrict__ mean, const float* __restrict__ inv,
    const float* __restrict__ gamma, const float* __restrict__ beta,
    float* __restrict__ Y, float* __restrict__ Z, int N) {
    __shared__ float4 As4[64 * 32];   // 64 rows x 128 k, k-contiguous f4, XOR swizzled
    __shared__ float4 Bs4[128 * 16];  // 128 k x 64 cols
    const int tid = threadIdx.x;
    const int rowBase = blockIdx.x * 64;
    const int colBase = blockIdx.y * 64;

#pragma unroll
    for (int i = 0; i < 8; ++i) {
        int f = tid + 256 * i;
        int row = f >> 5, c4 = f & 31;
        int grow = rowBase + row;
        float4 v = make_float4(0.f, 0.f, 0.f, 0.f);
        if (grow < N) {
            v = *(const float4*)&A[(size_t)grow * DIN + c4 * 4];
            if constexpr (NORM) {
                int k = c4 * 4;
                float4 m = *(const float4*)&mean[k];
                float4 iv = *(const float4*)&inv[k];
                float4 g = *(const float4*)&gamma[k];
                float4 bb = *(const float4*)&beta[k];
                v.x = frelu((v.x - m.x) * iv.x * g.x + bb.x);
                v.y = frelu((v.y - m.y) * iv.y * g.y + bb.y);
                v.z = frelu((v.z - m.z) * iv.z * g.z + bb.z);
                v.w = frelu((v.w - m.w) * iv.w * g.w + bb.w);
            }
        }
        As4[row * 32 + (c4 ^ ((row >> 2) & 7))] = v;
    }
#pragma unroll
    for (int i = 0; i < 8; ++i) {
        int f = tid + 256 * i;
        int k = f >> 4, c4f = f & 15;
        int gcol = colBase + c4f * 4;
        float4 v;
        if (gcol < WC) v = *(const float4*)&Brel[k * WC + gcol];
        else           v = *(const float4*)&Broot[k * WC + (gcol - WC)];
        Bs4[k * 16 + c4f] = v;
    }
    __syncthreads();

    const int rg = tid >> 4;
    const int cg = tid & 15;
    float acc[4][4];
#pragma unroll
    for (int r = 0; r < 4; ++r)
#pragma unroll
        for (int c = 0; c < 4; ++c) acc[r][c] = 0.f;

#pragma unroll 4
    for (int k0 = 0; k0 < 128; k0 += 4) {
        const int k4 = k0 >> 2;
        float4 a[4], bk[4];
#pragma unroll
        for (int j = 0; j < 4; ++j) a[j] = As4[(rg * 4 + j) * 32 + (k4 ^ (rg & 7))];
#pragma unroll
        for (int j = 0; j < 4; ++j) bk[j] = Bs4[(k0 + j) * 16 + cg];
#pragma unroll
        for (int r = 0; r < 4; ++r) {
            const float ar[4] = {a[r].x, a[r].y, a[r].z, a[r].w};
#pragma unroll
            for (int kk = 0; kk < 4; ++kk) {
                acc[r][0] += ar[kk] * bk[kk].x;
                acc[r][1] += ar[kk] * bk[kk].y;
                acc[r][2] += ar[kk] * bk[kk].z;
                acc[r][3] += ar[kk] * bk[kk].w;
            }
        }
    }

    const int c0g = colBase + cg * 4;
#pragma unroll
    for (int r = 0; r < 4; ++r) {
        int grow = rowBase + rg * 4 + r;
        if (grow < N) {
            float4 o = make_float4(acc[r][0], acc[r][1], acc[r][2], acc[r][3]);
            if (c0g < WC) {
                *(float4*)&Y[(size_t)grow * WC + c0g] = o;
            } else {
                int cz = c0g - WC;
                float4 bb = *(const float4*)&bias[cz];
                o.x += bb.x; o.y += bb.y; o.z += bb.z; o.w += bb.w;
                *(float4*)&Z[(size_t)grow * WC + cz] = o;
            }
        }
    }
}

// ---------------- Aggregation: h[n] = sum_{e} y[esrc[e]] + z[n]; replicated col stats ----------------
// h may alias z. gsum points at NREP replicated [2*DIMS] buffers.
template <int DIMS, int IT>
__global__ __launch_bounds__(256) void k_agg(
    const float* __restrict__ y, const float* z, float* h,
    const uint* __restrict__ off, const uint* __restrict__ esrc,
    float* __restrict__ gstat, int N) {
    constexpr int TPN = DIMS / 4;
    constexpr int G = 256 / TPN;
    const int tid = threadIdx.x;
    const int c4 = tid & (TPN - 1);
    const int g = tid / TPN;
    const int base = blockIdx.x * (G * IT);
    float4 ssum = make_float4(0.f, 0.f, 0.f, 0.f);
    float4 ssq = make_float4(0.f, 0.f, 0.f, 0.f);

    for (int it = 0; it < IT; ++it) {
        const int n = base + it * G + g;
        if (n < N) {
            const uint beg = off[n], end = off[n + 1];
            float4 acc = make_float4(0.f, 0.f, 0.f, 0.f);
            uint e = beg;
            // 4-wide unroll: 4 independent esrc loads then 4 independent row gathers in flight
            for (; e + 4 <= end; e += 4) {
                const uint s0 = esrc[e],     s1 = esrc[e + 1];
                const uint s2 = esrc[e + 2], s3 = esrc[e + 3];
                const float4 a0 = *(const float4*)&y[(size_t)s0 * DIMS + c4 * 4];
                const float4 a1 = *(const float4*)&y[(size_t)s1 * DIMS + c4 * 4];
                const float4 a2 = *(const float4*)&y[(size_t)s2 * DIMS + c4 * 4];
                const float4 a3 = *(const float4*)&y[(size_t)s3 * DIMS + c4 * 4];
                acc.x += (a0.x + a1.x) + (a2.x + a3.x);
                acc.y += (a0.y + a1.y) + (a2.y + a3.y);
                acc.z += (a0.z + a1.z) + (a2.z + a3.z);
                acc.w += (a0.w + a1.w) + (a2.w + a3.w);
            }
            for (; e < end; ++e) {
                const uint s0 = esrc[e];
                const float4 a0 = *(const float4*)&y[(size_t)s0 * DIMS + c4 * 4];
                acc.x += a0.x; acc.y += a0.y; acc.z += a0.z; acc.w += a0.w;
            }
            const size_t idx = (size_t)n * DIMS + c4 * 4;
            const vf4 zz = __builtin_nontemporal_load((const vf4*)&z[idx]);
            vf4 hh;
            hh.x = acc.x + zz.x; hh.y = acc.y + zz.y;
            hh.z = acc.z + zz.z; hh.w = acc.w + zz.w;
            __builtin_nontemporal_store(hh, (vf4*)&h[idx]);
            ssum.x += hh.x; ssum.y += hh.y; ssum.z += hh.z; ssum.w += hh.w;
            ssq.x += hh.x * hh.x; ssq.y += hh.y * hh.y;
            ssq.z += hh.z * hh.z; ssq.w += hh.w * hh.w;
        }
    }

    __shared__ float4 rsum[256];
    __shared__ float4 rsq[256];
    rsum[tid] = ssum;
    rsq[tid] = ssq;
    __syncthreads();
    if (g == 0) {
#pragma unroll
        for (int gg = 1; gg < G; ++gg) {
            float4 a = rsum[gg * TPN + c4];
            float4 b = rsq[gg * TPN + c4];
            ssum.x += a.x; ssum.y += a.y; ssum.z += a.z; ssum.w += a.w;
            ssq.x += b.x; ssq.y += b.y; ssq.z += b.z; ssq.w += b.w;
        }
        float* gs = gstat + (blockIdx.x & (NREP - 1)) * (2 * DIMS);
        const int cb = c4 * 4;
        unsafeAtomicAdd(&gs[cb + 0], ssum.x);
        unsafeAtomicAdd(&gs[cb + 1], ssum.y);
        unsafeAtomicAdd(&gs[cb + 2], ssum.z);
        unsafeAtomicAdd(&gs[cb + 3], ssum.w);
        unsafeAtomicAdd(&gs[DIMS + cb + 0], ssq.x);
        unsafeAtomicAdd(&gs[DIMS + cb + 1], ssq.y);
        unsafeAtomicAdd(&gs[DIMS + cb + 2], ssq.z);
        unsafeAtomicAdd(&gs[DIMS + cb + 3], ssq.w);
    }
}

// ---------------- finalize BN stats from NREP replicas ----------------
__global__ void k_finalize(const float* __restrict__ rep, float* __restrict__ mean,
                           float* __restrict__ inv, int C, float invN) {
    int c = threadIdx.x;
    if (c < C) {
        float s = 0.f, q = 0.f;
        for (int r = 0; r < NREP; ++r) {
            s += rep[r * 2 * C + c];
            q += rep[r * 2 * C + C + c];
        }
        float m = s * invN;
        float v = q * invN - m * m;
        mean[c] = m;
        inv[c] = rsqrtf(v + 1e-5f);
    }
}

// ---------------- final BN+relu elementwise ----------------
__global__ void k_out(const float* __restrict__ h2, const float* __restrict__ mean,
                      const float* __restrict__ inv, const float* __restrict__ gamma,
                      const float* __restrict__ beta, float* __restrict__ out, int nf4) {
    int i = blockIdx.x * blockDim.x + threadIdx.x;
    if (i < nf4) {
        int c = (i & 7) * 4;
        float4 h = ((const float4*)h2)[i];
        float4 m = *(const float4*)&mean[c];
        float4 iv = *(const float4*)&inv[c];
        float4 g = *(const float4*)&gamma[c];
        float4 b = *(const float4*)&beta[c];
        float4 o;
        o.x = frelu((h.x - m.x) * iv.x * g.x + b.x);
        o.y = frelu((h.y - m.y) * iv.y * g.y + b.y);
        o.z = frelu((h.z - m.z) * iv.z * g.z + b.z);
        o.w = frelu((h.w - m.w) * iv.w * g.w + b.w);
        ((float4*)out)[i] = o;
    }
}

extern "C" void kernel_launch(void* const* d_in, const int* in_sizes, int n_in,
                              void* d_out, int out_size, void* d_ws, size_t ws_size,
                              hipStream_t stream) {
    const float* x      = (const float*)d_in[0];
    const int*   eidx   = (const int*)d_in[1];
    const float* Wrel1  = (const float*)d_in[2];
    const float* brel1  = (const float*)d_in[3];
    const float* Wroot1 = (const float*)d_in[4];
    const float* gamma1 = (const float*)d_in[5];
    const float* beta1  = (const float*)d_in[6];
    const float* Wrel2  = (const float*)d_in[7];
    const float* brel2  = (const float*)d_in[8];
    const float* Wroot2 = (const float*)d_in[9];
    const float* gamma2 = (const float*)d_in[10];
    const float* beta2  = (const float*)d_in[11];

    const int N = in_sizes[0] / DIN;
    const int E = in_sizes[1] / 2;
    const int* src = eidx;
    const int* dst = eidx + E;

    char* p = (char*)d_ws;
    auto alloc = [&](size_t bytes) {
        void* r = (void*)p;
        p += (bytes + 255) & ~(size_t)255;
        return r;
    };
    uint*  cnt   = (uint*)alloc((size_t)N * 4);
    uint*  off   = (uint*)alloc((size_t)(N + 1) * 4);
    uint*  cur   = (uint*)alloc((size_t)N * 4);
    uint*  bsum  = (uint*)alloc(256 * 4);
    uint*  esrc  = (uint*)alloc((size_t)E * 4);
    float* y1    = (float*)alloc((size_t)N * DIN * 4);
    float* z1    = (float*)alloc((size_t)N * DIN * 4);   // h1 aliases z1
    float* y2    = (float*)alloc((size_t)N * DOUT * 4);
    float* z2    = (float*)alloc((size_t)N * DOUT * 4);  // h2 aliases z2
    // stats: s1rep[32][256] + s2rep[32][64] + mean1/inv1/mean2/inv2
    float* stats = (float*)alloc((size_t)(NREP * 2 * DIN + NREP * 2 * DOUT + 2 * DIN + 2 * DOUT) * 4);
    float* s1rep = stats;
    float* s2rep = stats + NREP * 2 * DIN;
    float* mean1 = s2rep + NREP * 2 * DOUT;
    float* inv1  = mean1 + DIN;
    float* mean2 = inv1 + DIN;
    float* inv2  = mean2 + DOUT;

    const float invN = 1.f / (float)N;
    const int nstats = NREP * 2 * DIN + NREP * 2 * DOUT;  // zero the replicas
    const int nb = (N + 1023) / 1024;

    int nz = N + nstats;
    k_zero<<<(nz + 255) / 256, 256, 0, stream>>>(cnt, N, stats, nstats);
    k_hist<<<(E + 255) / 256, 256, 0, stream>>>(dst, cnt, E);
    k_scan_part<<<nb, 256, 0, stream>>>(cnt, bsum, N);
    k_scan_top<<<1, 256, 0, stream>>>(bsum, off, nb, N, E);
    k_scan_fill<<<nb, 256, 0, stream>>>(cnt, bsum, off, cur, N);
    k_fill<<<(E + 255) / 256, 256, 0, stream>>>(src, dst, cur, esrc, E);
    // GEMM1  y1 = x@Wrel1, z1 = x@Wroot1 + brel1
    {
        dim3 grid((N + 63) / 64, (2 * DIN) / 64);
        k_gemm<DIN, false><<<grid, 256, 0, stream>>>(x, Wrel1, Wroot1, brel1,
                                                     nullptr, nullptr, nullptr, nullptr,
                                                     y1, z1, N);
    }
    // agg1 + stats (h1 -> z1): 16 nodes/block
    k_agg<DIN, 2><<<(N + 15) / 16, 256, 0, stream>>>(y1, z1, z1, off, esrc, s1rep, N);
    k_finalize<<<1, DIN, 0, stream>>>(s1rep, mean1, inv1, DIN, invN);
    // GEMM2 with fused BN1+relu on A
    {
        dim3 grid((N + 63) / 64, (2 * DOUT) / 64);
        k_gemm<DOUT, true><<<grid, 256, 0, stream>>>(z1, Wrel2, Wroot2, brel2,
                                                     mean1, inv1, gamma1, beta1,
                                                     y2, z2, N);
    }
    // agg2 + stats (h2 -> z2): 32 nodes/block
    k_agg<DOUT, 1><<<(N + 31) / 32, 256, 0, stream>>>(y2, z2, z2, off, esrc, s2rep, N);
    k_finalize<<<1, 64, 0, stream>>>(s2rep, mean2, inv2, DOUT, invN);
    int nf4 = N * DOUT / 4;
    k_out<<<(nf4 + 255) / 256, 256, 0, stream>>>(z2, mean2, inv2, gamma2, beta2,
                                                 (float*)d_out, nf4);
}

// Round 3
// 506.577 us; speedup vs baseline: 2.1484x; 1.2722x over previous
//
#include <hip/hip_runtime.h>
#include <hip/hip_bf16.h>
#include <stdint.h>

#define DIN 128
#define DOUT 32
#define NREP 32

typedef unsigned int uint;
typedef float f32x4 __attribute__((ext_vector_type(4)));
typedef _Float16 f16x8 __attribute__((ext_vector_type(8)));

__device__ __forceinline__ float frelu(float x) { return x > 0.f ? x : 0.f; }

// ---------------- K1: zero counts + stat accumulators ----------------
__global__ void k_zero(uint* __restrict__ cnt, int ncnt, float* __restrict__ stats, int nstats) {
    int i = blockIdx.x * blockDim.x + threadIdx.x;
    if (i < ncnt) cnt[i] = 0u;
    else if (i < ncnt + nstats) stats[i - ncnt] = 0.f;
}

// ---------------- K2: histogram of dst ----------------
__global__ void k_hist(const int* __restrict__ dst, uint* __restrict__ cnt, int E) {
    int e = blockIdx.x * blockDim.x + threadIdx.x;
    if (e < E) atomicAdd(&cnt[dst[e]], 1u);
}

// ---------------- K3a: per-block (1024-elem) sums ----------------
__global__ __launch_bounds__(256) void k_scan_part(const uint* __restrict__ cnt,
                                                   uint* __restrict__ bsum, int N) {
    __shared__ uint red[256];
    const int t = threadIdx.x;
    const int base = blockIdx.x * 1024 + t * 4;
    uint s = 0;
    if (base + 3 < N) {
        uint4 v = *(const uint4*)&cnt[base];
        s = v.x + v.y + v.z + v.w;
    } else {
        for (int i = 0; i < 4; ++i)
            if (base + i < N) s += cnt[base + i];
    }
    red[t] = s;
    __syncthreads();
    for (int ofs = 128; ofs > 0; ofs >>= 1) {
        if (t < ofs) red[t] += red[t + ofs];
        __syncthreads();
    }
    if (t == 0) bsum[blockIdx.x] = red[0];
}

// ---------------- K3b: exclusive scan of block sums (nb <= 256) ----------------
__global__ __launch_bounds__(256) void k_scan_top(uint* __restrict__ bsum, uint* __restrict__ off,
                                                  int nb, int N, int E) {
    __shared__ uint ps[256];
    const int t = threadIdx.x;
    uint v = (t < nb) ? bsum[t] : 0u;
    ps[t] = v;
    __syncthreads();
    for (int ofs = 1; ofs < 256; ofs <<= 1) {
        uint u = (t >= ofs) ? ps[t - ofs] : 0u;
        __syncthreads();
        ps[t] += u;
        __syncthreads();
    }
    if (t < nb) bsum[t] = ps[t] - v;  // exclusive
    if (t == 0) off[N] = (uint)E;
}

// ---------------- K3c: block-local exclusive scan + base -> off, cur ----------------
__global__ __launch_bounds__(256) void k_scan_fill(const uint* __restrict__ cnt,
                                                   const uint* __restrict__ bsum,
                                                   uint* __restrict__ off, uint* __restrict__ cur,
                                                   int N) {
    __shared__ uint ps[256];
    const int t = threadIdx.x;
    const int base = blockIdx.x * 1024 + t * 4;
    uint v[4];
    uint s = 0;
#pragma unroll
    for (int i = 0; i < 4; ++i) {
        uint c = (base + i < N) ? cnt[base + i] : 0u;
        v[i] = s;
        s += c;
    }
    ps[t] = s;
    __syncthreads();
    for (int ofs = 1; ofs < 256; ofs <<= 1) {
        uint u = (t >= ofs) ? ps[t - ofs] : 0u;
        __syncthreads();
        ps[t] += u;
        __syncthreads();
    }
    const uint tp = ps[t] - s + bsum[blockIdx.x];
#pragma unroll
    for (int i = 0; i < 4; ++i) {
        int idx = base + i;
        if (idx < N) {
            uint o = tp + v[i];
            off[idx] = o;
            cur[idx] = o;
        }
    }
}

// ---------------- K4: fill CSR edge array ----------------
__global__ void k_fill(const int* __restrict__ src, const int* __restrict__ dst,
                       uint* __restrict__ cur, uint* __restrict__ esrc, int E) {
    int e = blockIdx.x * blockDim.x + threadIdx.x;
    if (e < E) {
        int d = dst[e];
        uint p = atomicAdd(&cur[d], 1u);
        esrc[p] = (uint)src[e];
    }
}

// ---------------- K5: transpose+convert weights to fp16 Bt[outcol][k] ----------------
// Bt1: rows 0..127 = Wrel1 cols, 128..255 = Wroot1 cols. Bt2: 0..31 = Wrel2, 32..63 = Wroot2.
__global__ void k_prepw(const float* __restrict__ Wrel1, const float* __restrict__ Wroot1,
                        const float* __restrict__ Wrel2, const float* __restrict__ Wroot2,
                        _Float16* __restrict__ Bt1, _Float16* __restrict__ Bt2) {
    const int c = blockIdx.x;
    const int k = threadIdx.x;  // 128 threads = K
    if (c < 256) {
        const float* W = (c < 128) ? Wrel1 : Wroot1;
        int cl = c & 127;
        Bt1[c * 128 + k] = (_Float16)W[k * 128 + cl];
    } else {
        int c2 = c - 256;  // 0..63
        const float* W = (c2 < 32) ? Wrel2 : Wroot2;
        int cl = c2 & 31;
        Bt2[c2 * 128 + k] = (_Float16)W[k * 32 + cl];
    }
}

// ---------------- MFMA GEMM: [Y | Z] = A16 @ Bt^T ; Y fp16, Z fp32 + bias ----------------
// A [N][128] f32 (optionally BN+relu on load). Bt [2*WC][128] fp16 (row = output col).
// Block 256 thr = 4 waves; tile 64 rows x 64 cols; K=128 single shot.
template <int WC, bool NORM>
__global__ __launch_bounds__(256) void k_gemm(
    const float* __restrict__ A, const _Float16* __restrict__ Bt,
    const float* __restrict__ bias,
    const float* __restrict__ mean, const float* __restrict__ inv,
    const float* __restrict__ gamma, const float* __restrict__ beta,
    _Float16* __restrict__ Y, float* __restrict__ Z, int N) {
    __shared__ __align__(16) char smem[32768];  // As 16KB | Bs 16KB ; Cs aliases (17408B)
    const int tid = threadIdx.x;
    const int rowBase = blockIdx.x * 64;
    const int colBase = blockIdx.y * 64;

    // stage A: fp32 -> fp16, LDS [64][128] fp16, byte ^= (row&7)<<4
#pragma unroll
    for (int i = 0; i < 8; ++i) {
        int f = tid + 256 * i;
        int row = f >> 5, c4 = f & 31;
        int grow = rowBase + row;
        float4 v = make_float4(0.f, 0.f, 0.f, 0.f);
        if (grow < N) {
            v = *(const float4*)&A[(size_t)grow * DIN + c4 * 4];
            if constexpr (NORM) {
                int k = c4 * 4;
                float4 m = *(const float4*)&mean[k];
                float4 iv = *(const float4*)&inv[k];
                float4 g = *(const float4*)&gamma[k];
                float4 bb = *(const float4*)&beta[k];
                v.x = frelu((v.x - m.x) * iv.x * g.x + bb.x);
                v.y = frelu((v.y - m.y) * iv.y * g.y + bb.y);
                v.z = frelu((v.z - m.z) * iv.z * g.z + bb.z);
                v.w = frelu((v.w - m.w) * iv.w * g.w + bb.w);
            }
        }
        union { short4 s; _Float16 h[4]; } u;
        u.h[0] = (_Float16)v.x; u.h[1] = (_Float16)v.y;
        u.h[2] = (_Float16)v.z; u.h[3] = (_Float16)v.w;
        int off = row * 256 + ((c4 * 8) ^ ((row & 7) << 4));
        *(short4*)(smem + off) = u.s;
    }
    // stage B: Bt rows [colBase, colBase+64), same layout/swizzle
#pragma unroll
    for (int i = 0; i < 4; ++i) {
        int f = tid + 256 * i;
        int row = f >> 4, sl = f & 15;
        f16x8 v = *(const f16x8*)&Bt[(size_t)(colBase + row) * 128 + sl * 8];
        int off = row * 256 + ((sl * 16) ^ ((row & 7) << 4));
        *(f16x8*)(smem + 16384 + off) = v;
    }
    __syncthreads();

    const int lane = tid & 63;
    const int w = tid >> 6;
    const int wrow = (w >> 1) * 32;
    const int wcol = (w & 1) * 32;
    const int lr = lane & 15;
    const int lk = lane >> 4;

    f32x4 acc[2][2] = {};
#pragma unroll
    for (int s = 0; s < 4; ++s) {
        f16x8 a[2], b[2];
#pragma unroll
        for (int m = 0; m < 2; ++m) {
            int row = wrow + m * 16 + lr;
            int off = row * 256 + (((s * 64) + lk * 16) ^ ((row & 7) << 4));
            a[m] = *(const f16x8*)(smem + off);
        }
#pragma unroll
        for (int n = 0; n < 2; ++n) {
            int col = wcol + n * 16 + lr;
            int off = col * 256 + (((s * 64) + lk * 16) ^ ((col & 7) << 4));
            b[n] = *(const f16x8*)(smem + 16384 + off);
        }
#pragma unroll
        for (int m = 0; m < 2; ++m)
#pragma unroll
            for (int n = 0; n < 2; ++n)
                acc[m][n] = __builtin_amdgcn_mfma_f32_16x16x32_f16(a[m], b[n], acc[m][n], 0, 0, 0);
    }

    __syncthreads();
    // acc -> Cs [64][68] f32 (aliases smem)
    float* Cs = (float*)smem;
#pragma unroll
    for (int m = 0; m < 2; ++m)
#pragma unroll
        for (int n = 0; n < 2; ++n) {
            int r0 = wrow + m * 16 + (lane >> 4) * 4;
            int c = wcol + n * 16 + (lane & 15);
#pragma unroll
            for (int j = 0; j < 4; ++j) Cs[(r0 + j) * 68 + c] = acc[m][n][j];
        }
    __syncthreads();

    // cooperative coalesced store: thread t -> row t>>2, cols (t&3)*16..+16
    {
        int row = tid >> 2, cq = tid & 3;
        int grow = rowBase + row;
        if (grow < N) {
            const int cb = row * 68 + cq * 16;
            f32x4 t0 = *(const f32x4*)&Cs[cb + 0];
            f32x4 t1 = *(const f32x4*)&Cs[cb + 4];
            f32x4 t2 = *(const f32x4*)&Cs[cb + 8];
            f32x4 t3 = *(const f32x4*)&Cs[cb + 12];
            int gc0 = colBase + cq * 16;
            if (gc0 < WC) {  // Y (fp16)
                f16x8 h0, h1;
                h0[0] = (_Float16)t0.x; h0[1] = (_Float16)t0.y; h0[2] = (_Float16)t0.z; h0[3] = (_Float16)t0.w;
                h0[4] = (_Float16)t1.x; h0[5] = (_Float16)t1.y; h0[6] = (_Float16)t1.z; h0[7] = (_Float16)t1.w;
                h1[0] = (_Float16)t2.x; h1[1] = (_Float16)t2.y; h1[2] = (_Float16)t2.z; h1[3] = (_Float16)t2.w;
                h1[4] = (_Float16)t3.x; h1[5] = (_Float16)t3.y; h1[6] = (_Float16)t3.z; h1[7] = (_Float16)t3.w;
                *(f16x8*)&Y[(size_t)grow * WC + gc0] = h0;
                *(f16x8*)&Y[(size_t)grow * WC + gc0 + 8] = h1;
            } else {  // Z (fp32) + bias
                int zc = gc0 - WC;
                f32x4 b0 = *(const f32x4*)&bias[zc + 0];
                f32x4 b1 = *(const f32x4*)&bias[zc + 4];
                f32x4 b2 = *(const f32x4*)&bias[zc + 8];
                f32x4 b3 = *(const f32x4*)&bias[zc + 12];
                t0 += b0; t1 += b1; t2 += b2; t3 += b3;
                *(f32x4*)&Z[(size_t)grow * WC + zc + 0] = t0;
                *(f32x4*)&Z[(size_t)grow * WC + zc + 4] = t1;
                *(f32x4*)&Z[(size_t)grow * WC + zc + 8] = t2;
                *(f32x4*)&Z[(size_t)grow * WC + zc + 12] = t3;
            }
        }
    }
}

// ---------------- Aggregation: h[n] = sum_e y16[esrc[e]] + z[n]; replicated col stats ----------------
template <int DIMS, int IT>
__global__ __launch_bounds__(256) void k_agg(
    const _Float16* __restrict__ y, const float* z, float* h,
    const uint* __restrict__ off, const uint* __restrict__ esrc,
    float* __restrict__ gstat, int N) {
    constexpr int TPN = DIMS / 8;   // threads per node (16 or 4)
    constexpr int G = 256 / TPN;
    const int tid = threadIdx.x;
    const int c8 = tid & (TPN - 1);
    const int g = tid / TPN;
    const int col0 = c8 * 8;
    const int base = blockIdx.x * (G * IT);
    float ssum[8] = {0, 0, 0, 0, 0, 0, 0, 0};
    float ssq[8] = {0, 0, 0, 0, 0, 0, 0, 0};

    for (int it = 0; it < IT; ++it) {
        const int n = base + it * G + g;
        if (n < N) {
            const uint beg = off[n], end = off[n + 1];
            float acc[8] = {0, 0, 0, 0, 0, 0, 0, 0};
            uint e = beg;
            for (; e + 4 <= end; e += 4) {
                const uint s0 = esrc[e], s1 = esrc[e + 1];
                const uint s2 = esrc[e + 2], s3 = esrc[e + 3];
                const f16x8 a0 = *(const f16x8*)&y[(size_t)s0 * DIMS + col0];
                const f16x8 a1 = *(const f16x8*)&y[(size_t)s1 * DIMS + col0];
                const f16x8 a2 = *(const f16x8*)&y[(size_t)s2 * DIMS + col0];
                const f16x8 a3 = *(const f16x8*)&y[(size_t)s3 * DIMS + col0];
#pragma unroll
                for (int j = 0; j < 8; ++j)
                    acc[j] += ((float)a0[j] + (float)a1[j]) + ((float)a2[j] + (float)a3[j]);
            }
            for (; e < end; ++e) {
                const uint s0 = esrc[e];
                const f16x8 a0 = *(const f16x8*)&y[(size_t)s0 * DIMS + col0];
#pragma unroll
                for (int j = 0; j < 8; ++j) acc[j] += (float)a0[j];
            }
            const size_t idx = (size_t)n * DIMS + col0;
            f32x4 z0 = __builtin_nontemporal_load((const f32x4*)&z[idx]);
            f32x4 z1 = __builtin_nontemporal_load((const f32x4*)&z[idx + 4]);
            float hv[8];
            hv[0] = acc[0] + z0.x; hv[1] = acc[1] + z0.y; hv[2] = acc[2] + z0.z; hv[3] = acc[3] + z0.w;
            hv[4] = acc[4] + z1.x; hv[5] = acc[5] + z1.y; hv[6] = acc[6] + z1.z; hv[7] = acc[7] + z1.w;
            f32x4 h0 = {hv[0], hv[1], hv[2], hv[3]};
            f32x4 h1 = {hv[4], hv[5], hv[6], hv[7]};
            __builtin_nontemporal_store(h0, (f32x4*)&h[idx]);
            __builtin_nontemporal_store(h1, (f32x4*)&h[idx + 4]);
#pragma unroll
            for (int j = 0; j < 8; ++j) {
                ssum[j] += hv[j];
                ssq[j] += hv[j] * hv[j];
            }
        }
    }

    __shared__ f32x4 red[256][4];
    red[tid][0] = (f32x4){ssum[0], ssum[1], ssum[2], ssum[3]};
    red[tid][1] = (f32x4){ssum[4], ssum[5], ssum[6], ssum[7]};
    red[tid][2] = (f32x4){ssq[0], ssq[1], ssq[2], ssq[3]};
    red[tid][3] = (f32x4){ssq[4], ssq[5], ssq[6], ssq[7]};
    __syncthreads();
    for (int st = G / 2; st >= 1; st >>= 1) {
        if (g < st) {
#pragma unroll
            for (int q = 0; q < 4; ++q) red[tid][q] += red[tid + st * TPN][q];
        }
        __syncthreads();
    }
    if (g == 0) {
        float* gs = gstat + (blockIdx.x & (NREP - 1)) * (2 * DIMS);
        f32x4 s0 = red[c8][0], s1 = red[c8][1], q0 = red[c8][2], q1 = red[c8][3];
        unsafeAtomicAdd(&gs[col0 + 0], s0.x);
        unsafeAtomicAdd(&gs[col0 + 1], s0.y);
        unsafeAtomicAdd(&gs[col0 + 2], s0.z);
        unsafeAtomicAdd(&gs[col0 + 3], s0.w);
        unsafeAtomicAdd(&gs[col0 + 4], s1.x);
        unsafeAtomicAdd(&gs[col0 + 5], s1.y);
        unsafeAtomicAdd(&gs[col0 + 6], s1.z);
        unsafeAtomicAdd(&gs[col0 + 7], s1.w);
        unsafeAtomicAdd(&gs[DIMS + col0 + 0], q0.x);
        unsafeAtomicAdd(&gs[DIMS + col0 + 1], q0.y);
        unsafeAtomicAdd(&gs[DIMS + col0 + 2], q0.z);
        unsafeAtomicAdd(&gs[DIMS + col0 + 3], q0.w);
        unsafeAtomicAdd(&gs[DIMS + col0 + 4], q1.x);
        unsafeAtomicAdd(&gs[DIMS + col0 + 5], q1.y);
        unsafeAtomicAdd(&gs[DIMS + col0 + 6], q1.z);
        unsafeAtomicAdd(&gs[DIMS + col0 + 7], q1.w);
    }
}

// ---------------- finalize BN stats from NREP replicas ----------------
__global__ void k_finalize(const float* __restrict__ rep, float* __restrict__ mean,
                           float* __restrict__ inv, int C, float invN) {
    int c = threadIdx.x;
    if (c < C) {
        float s = 0.f, q = 0.f;
        for (int r = 0; r < NREP; ++r) {
            s += rep[r * 2 * C + c];
            q += rep[r * 2 * C + C + c];
        }
        float m = s * invN;
        float v = q * invN - m * m;
        mean[c] = m;
        inv[c] = rsqrtf(v + 1e-5f);
    }
}

// ---------------- final BN+relu elementwise ----------------
__global__ void k_out(const float* __restrict__ h2, const float* __restrict__ mean,
                      const float* __restrict__ inv, const float* __restrict__ gamma,
                      const float* __restrict__ beta, float* __restrict__ out, int nf4) {
    int i = blockIdx.x * blockDim.x + threadIdx.x;
    if (i < nf4) {
        int c = (i & 7) * 4;
        float4 h = ((const float4*)h2)[i];
        float4 m = *(const float4*)&mean[c];
        float4 iv = *(const float4*)&inv[c];
        float4 g = *(const float4*)&gamma[c];
        float4 b = *(const float4*)&beta[c];
        float4 o;
        o.x = frelu((h.x - m.x) * iv.x * g.x + b.x);
        o.y = frelu((h.y - m.y) * iv.y * g.y + b.y);
        o.z = frelu((h.z - m.z) * iv.z * g.z + b.z);
        o.w = frelu((h.w - m.w) * iv.w * g.w + b.w);
        ((float4*)out)[i] = o;
    }
}

extern "C" void kernel_launch(void* const* d_in, const int* in_sizes, int n_in,
                              void* d_out, int out_size, void* d_ws, size_t ws_size,
                              hipStream_t stream) {
    const float* x      = (const float*)d_in[0];
    const int*   eidx   = (const int*)d_in[1];
    const float* Wrel1  = (const float*)d_in[2];
    const float* brel1  = (const float*)d_in[3];
    const float* Wroot1 = (const float*)d_in[4];
    const float* gamma1 = (const float*)d_in[5];
    const float* beta1  = (const float*)d_in[6];
    const float* Wrel2  = (const float*)d_in[7];
    const float* brel2  = (const float*)d_in[8];
    const float* Wroot2 = (const float*)d_in[9];
    const float* gamma2 = (const float*)d_in[10];
    const float* beta2  = (const float*)d_in[11];

    const int N = in_sizes[0] / DIN;
    const int E = in_sizes[1] / 2;
    const int* src = eidx;
    const int* dst = eidx + E;

    char* p = (char*)d_ws;
    auto alloc = [&](size_t bytes) {
        void* r = (void*)p;
        p += (bytes + 255) & ~(size_t)255;
        return r;
    };
    uint*      cnt  = (uint*)alloc((size_t)N * 4);
    uint*      off  = (uint*)alloc((size_t)(N + 1) * 4);
    uint*      cur  = (uint*)alloc((size_t)N * 4);
    uint*      bsum = (uint*)alloc(256 * 4);
    uint*      esrc = (uint*)alloc((size_t)E * 4);
    _Float16*  Bt1  = (_Float16*)alloc(256 * 128 * 2);
    _Float16*  Bt2  = (_Float16*)alloc(64 * 128 * 2);
    _Float16*  y1   = (_Float16*)alloc((size_t)N * DIN * 2);
    float*     z1   = (float*)alloc((size_t)N * DIN * 4);   // h1 aliases z1
    _Float16*  y2   = (_Float16*)alloc((size_t)N * DOUT * 2);
    float*     z2   = (float*)alloc((size_t)N * DOUT * 4);  // h2 aliases z2
    float*     stats = (float*)alloc((size_t)(NREP * 2 * DIN + NREP * 2 * DOUT + 2 * DIN + 2 * DOUT) * 4);
    float* s1rep = stats;
    float* s2rep = stats + NREP * 2 * DIN;
    float* mean1 = s2rep + NREP * 2 * DOUT;
    float* inv1  = mean1 + DIN;
    float* mean2 = inv1 + DIN;
    float* inv2  = mean2 + DOUT;

    const float invN = 1.f / (float)N;
    const int nstats = NREP * 2 * DIN + NREP * 2 * DOUT;
    const int nb = (N + 1023) / 1024;
    const int nb64 = (N + 63) / 64;

    int nz = N + nstats;
    k_zero<<<(nz + 255) / 256, 256, 0, stream>>>(cnt, N, stats, nstats);
    k_hist<<<(E + 255) / 256, 256, 0, stream>>>(dst, cnt, E);
    k_scan_part<<<nb, 256, 0, stream>>>(cnt, bsum, N);
    k_scan_top<<<1, 256, 0, stream>>>(bsum, off, nb, N, E);
    k_scan_fill<<<nb, 256, 0, stream>>>(cnt, bsum, off, cur, N);
    k_fill<<<(E + 255) / 256, 256, 0, stream>>>(src, dst, cur, esrc, E);
    k_prepw<<<320, 128, 0, stream>>>(Wrel1, Wroot1, Wrel2, Wroot2, Bt1, Bt2);

    // GEMM1: y1 (fp16) = x@Wrel1 ; z1 (fp32) = x@Wroot1 + brel1
    k_gemm<DIN, false><<<dim3(nb64, 4), 256, 0, stream>>>(
        x, Bt1, brel1, nullptr, nullptr, nullptr, nullptr, y1, z1, N);
    // agg1 + stats (h1 -> z1)
    k_agg<DIN, 2><<<(N + 31) / 32, 256, 0, stream>>>(y1, z1, z1, off, esrc, s1rep, N);
    k_finalize<<<1, DIN, 0, stream>>>(s1rep, mean1, inv1, DIN, invN);
    // GEMM2 with fused BN1+relu on A
    k_gemm<DOUT, true><<<dim3(nb64, 1), 256, 0, stream>>>(
        z1, Bt2, brel2, mean1, inv1, gamma1, beta1, y2, z2, N);
    // agg2 + stats (h2 -> z2)
    k_agg<DOUT, 1><<<(N + 63) / 64, 256, 0, stream>>>(y2, z2, z2, off, esrc, s2rep, N);
    k_finalize<<<1, 64, 0, stream>>>(s2rep, mean2, inv2, DOUT, invN);
    int nf4 = N * DOUT / 4;
    k_out<<<(nf4 + 255) / 256, 256, 0, stream>>>(z2, mean2, inv2, gamma2, beta2,
                                                 (float*)d_out, nf4);
}

// Round 4
// 349.586 us; speedup vs baseline: 3.1132x; 1.4491x over previous
//
#include <hip/hip_runtime.h>
#include <hip/hip_bf16.h>
#include <stdint.h>

#define DIN 128
#define DOUT 32
#define NREP 32
#define BKT_SHIFT 9
#define BKT_NODES 512
#define MAXBE 12288

typedef unsigned int uint;
typedef float f32x4 __attribute__((ext_vector_type(4)));
typedef _Float16 f16x8 __attribute__((ext_vector_type(8)));

__device__ __forceinline__ float frelu(float x) { return x > 0.f ? x : 0.f; }

// ---------------- K0: zero bucket counts + stat accumulators ----------------
__global__ void k_zero(uint* __restrict__ bcnt, int nb, float* __restrict__ stats, int nstats) {
    int i = blockIdx.x * blockDim.x + threadIdx.x;
    if (i < nb) bcnt[i] = 0u;
    else if (i < nb + nstats) stats[i - nb] = 0.f;
}

// ---------------- K1: bucket histogram (dst>>9), LDS-staged ----------------
__global__ __launch_bounds__(256) void k_bhist(const int* __restrict__ dst,
                                               uint* __restrict__ bcnt, int E, int nbuck) {
    __shared__ uint lh[256];
    const int t = threadIdx.x;
    lh[t] = 0;
    __syncthreads();
    const int base = blockIdx.x * 8192;
#pragma unroll 8
    for (int i = 0; i < 32; ++i) {
        int e = base + t + 256 * i;
        if (e < E) atomicAdd(&lh[((uint)dst[e]) >> BKT_SHIFT], 1u);
    }
    __syncthreads();
    if (t < nbuck && lh[t]) atomicAdd(&bcnt[t], lh[t]);
}

// ---------------- K2: scan bucket counts -> boff, gcur ----------------
__global__ __launch_bounds__(256) void k_bscan(const uint* __restrict__ bcnt,
                                               uint* __restrict__ boff, uint* __restrict__ gcur,
                                               int nbuck, int E) {
    __shared__ uint ps[256];
    const int t = threadIdx.x;
    uint v = (t < nbuck) ? bcnt[t] : 0u;
    ps[t] = v;
    __syncthreads();
    for (int o = 1; o < 256; o <<= 1) {
        uint u = (t >= o) ? ps[t - o] : 0u;
        __syncthreads();
        ps[t] += u;
        __syncthreads();
    }
    if (t < nbuck) {
        uint ex = ps[t] - v;
        boff[t] = ex;
        gcur[t] = ex;
    }
    if (t == 0) boff[nbuck] = (uint)E;
}

// ---------------- K3: partition edges into bucket-contiguous packed array ----------------
// gbuf[pos] = (dstLocal<<17) | src
__global__ __launch_bounds__(256) void k_part(const int* __restrict__ src,
                                              const int* __restrict__ dst,
                                              uint* __restrict__ gcur, uint* __restrict__ gbuf,
                                              int E, int nbuck) {
    __shared__ uint lh[256], lb[256], lc[256];
    const int t = threadIdx.x;
    lh[t] = 0;
    lc[t] = 0;
    __syncthreads();
    const int base = blockIdx.x * 8192;
#pragma unroll 8
    for (int i = 0; i < 32; ++i) {
        int e = base + t + 256 * i;
        if (e < E) atomicAdd(&lh[((uint)dst[e]) >> BKT_SHIFT], 1u);
    }
    __syncthreads();
    if (t < nbuck && lh[t]) lb[t] = atomicAdd(&gcur[t], lh[t]);
    __syncthreads();
#pragma unroll 8
    for (int i = 0; i < 32; ++i) {
        int e = base + t + 256 * i;
        if (e < E) {
            uint d = (uint)dst[e];
            uint s = (uint)src[e];
            uint b = d >> BKT_SHIFT;
            uint r = atomicAdd(&lc[b], 1u);
            gbuf[lb[b] + r] = ((d & (BKT_NODES - 1)) << 17) | s;
        }
    }
}

// ---------------- K4: per-bucket local CSR: off + esrc ----------------
__global__ __launch_bounds__(256) void k_csr(const uint* __restrict__ boff,
                                             const uint* __restrict__ gbuf,
                                             uint* __restrict__ off, uint* __restrict__ esrc,
                                             int N, int E, int nbuck) {
    __shared__ uint ed[MAXBE];
    __shared__ uint lh[BKT_NODES];
    __shared__ uint lsc[BKT_NODES];
    __shared__ uint ps[256];
    const int b = blockIdx.x, t = threadIdx.x;
    const uint bb = boff[b];
    int cnt = (int)(boff[b + 1] - bb);
    if (cnt > MAXBE) cnt = MAXBE;
    for (int i = t; i < cnt; i += 256) ed[i] = gbuf[bb + i];
    lh[t] = 0;
    lh[t + 256] = 0;
    __syncthreads();
    for (int i = t; i < cnt; i += 256) atomicAdd(&lh[ed[i] >> 17], 1u);
    __syncthreads();
    const uint v0 = lh[2 * t], v1 = lh[2 * t + 1];
    ps[t] = v0 + v1;
    __syncthreads();
    for (int o = 1; o < 256; o <<= 1) {
        uint u = (t >= o) ? ps[t - o] : 0u;
        __syncthreads();
        ps[t] += u;
        __syncthreads();
    }
    const uint ex = ps[t] - (v0 + v1);
    lsc[2 * t] = ex;
    lsc[2 * t + 1] = ex + v0;
    const int n0 = b << BKT_SHIFT;
    if (n0 + 2 * t < N) off[n0 + 2 * t] = bb + ex;
    if (n0 + 2 * t + 1 < N) off[n0 + 2 * t + 1] = bb + ex + v0;
    if (b == nbuck - 1 && t == 0) off[N] = (uint)E;
    __syncthreads();
    for (int i = t; i < cnt; i += 256) {
        uint p = ed[i];
        uint r = atomicAdd(&lsc[p >> 17], 1u);
        esrc[bb + r] = p & 0x1FFFFu;
    }
}

// ---------------- K5: transpose+convert weights to fp16 Bt[outcol][k] ----------------
__global__ void k_prepw(const float* __restrict__ Wrel1, const float* __restrict__ Wroot1,
                        const float* __restrict__ Wrel2, const float* __restrict__ Wroot2,
                        _Float16* __restrict__ Bt1, _Float16* __restrict__ Bt2) {
    const int c = blockIdx.x;
    const int k = threadIdx.x;
    if (c < 256) {
        const float* W = (c < 128) ? Wrel1 : Wroot1;
        int cl = c & 127;
        Bt1[c * 128 + k] = (_Float16)W[k * 128 + cl];
    } else {
        int c2 = c - 256;
        const float* W = (c2 < 32) ? Wrel2 : Wroot2;
        int cl = c2 & 31;
        Bt2[c2 * 128 + k] = (_Float16)W[k * 32 + cl];
    }
}

// ---------------- MFMA GEMM: [Y | Z] = A16 @ Bt^T ; Y fp16, Z fp32 + bias ----------------
template <int WC, bool NORM>
__global__ __launch_bounds__(256) void k_gemm(
    const float* __restrict__ A, const _Float16* __restrict__ Bt,
    const float* __restrict__ bias,
    const float* __restrict__ mean, const float* __restrict__ inv,
    const float* __restrict__ gamma, const float* __restrict__ beta,
    _Float16* __restrict__ Y, float* __restrict__ Z, int N) {
    __shared__ __align__(16) char smem[32768];
    const int tid = threadIdx.x;
    const int rowBase = blockIdx.x * 64;
    const int colBase = blockIdx.y * 64;

#pragma unroll
    for (int i = 0; i < 8; ++i) {
        int f = tid + 256 * i;
        int row = f >> 5, c4 = f & 31;
        int grow = rowBase + row;
        float4 v = make_float4(0.f, 0.f, 0.f, 0.f);
        if (grow < N) {
            v = *(const float4*)&A[(size_t)grow * DIN + c4 * 4];
            if constexpr (NORM) {
                int k = c4 * 4;
                float4 m = *(const float4*)&mean[k];
                float4 iv = *(const float4*)&inv[k];
                float4 g = *(const float4*)&gamma[k];
                float4 bb = *(const float4*)&beta[k];
                v.x = frelu((v.x - m.x) * iv.x * g.x + bb.x);
                v.y = frelu((v.y - m.y) * iv.y * g.y + bb.y);
                v.z = frelu((v.z - m.z) * iv.z * g.z + bb.z);
                v.w = frelu((v.w - m.w) * iv.w * g.w + bb.w);
            }
        }
        union { short4 s; _Float16 h[4]; } u;
        u.h[0] = (_Float16)v.x; u.h[1] = (_Float16)v.y;
        u.h[2] = (_Float16)v.z; u.h[3] = (_Float16)v.w;
        int off = row * 256 + ((c4 * 8) ^ ((row & 7) << 4));
        *(short4*)(smem + off) = u.s;
    }
#pragma unroll
    for (int i = 0; i < 4; ++i) {
        int f = tid + 256 * i;
        int row = f >> 4, sl = f & 15;
        f16x8 v = *(const f16x8*)&Bt[(size_t)(colBase + row) * 128 + sl * 8];
        int off = row * 256 + ((sl * 16) ^ ((row & 7) << 4));
        *(f16x8*)(smem + 16384 + off) = v;
    }
    __syncthreads();

    const int lane = tid & 63;
    const int w = tid >> 6;
    const int wrow = (w >> 1) * 32;
    const int wcol = (w & 1) * 32;
    const int lr = lane & 15;
    const int lk = lane >> 4;

    f32x4 acc[2][2] = {};
#pragma unroll
    for (int s = 0; s < 4; ++s) {
        f16x8 a[2], b[2];
#pragma unroll
        for (int m = 0; m < 2; ++m) {
            int row = wrow + m * 16 + lr;
            int off = row * 256 + (((s * 64) + lk * 16) ^ ((row & 7) << 4));
            a[m] = *(const f16x8*)(smem + off);
        }
#pragma unroll
        for (int n = 0; n < 2; ++n) {
            int col = wcol + n * 16 + lr;
            int off = col * 256 + (((s * 64) + lk * 16) ^ ((col & 7) << 4));
            b[n] = *(const f16x8*)(smem + 16384 + off);
        }
#pragma unroll
        for (int m = 0; m < 2; ++m)
#pragma unroll
            for (int n = 0; n < 2; ++n)
                acc[m][n] = __builtin_amdgcn_mfma_f32_16x16x32_f16(a[m], b[n], acc[m][n], 0, 0, 0);
    }

    __syncthreads();
    float* Cs = (float*)smem;
#pragma unroll
    for (int m = 0; m < 2; ++m)
#pragma unroll
        for (int n = 0; n < 2; ++n) {
            int r0 = wrow + m * 16 + (lane >> 4) * 4;
            int c = wcol + n * 16 + (lane & 15);
#pragma unroll
            for (int j = 0; j < 4; ++j) Cs[(r0 + j) * 68 + c] = acc[m][n][j];
        }
    __syncthreads();

    {
        int row = tid >> 2, cq = tid & 3;
        int grow = rowBase + row;
        if (grow < N) {
            const int cb = row * 68 + cq * 16;
            f32x4 t0 = *(const f32x4*)&Cs[cb + 0];
            f32x4 t1 = *(const f32x4*)&Cs[cb + 4];
            f32x4 t2 = *(const f32x4*)&Cs[cb + 8];
            f32x4 t3 = *(const f32x4*)&Cs[cb + 12];
            int gc0 = colBase + cq * 16;
            if (gc0 < WC) {
                f16x8 h0, h1;
                h0[0] = (_Float16)t0.x; h0[1] = (_Float16)t0.y; h0[2] = (_Float16)t0.z; h0[3] = (_Float16)t0.w;
                h0[4] = (_Float16)t1.x; h0[5] = (_Float16)t1.y; h0[6] = (_Float16)t1.z; h0[7] = (_Float16)t1.w;
                h1[0] = (_Float16)t2.x; h1[1] = (_Float16)t2.y; h1[2] = (_Float16)t2.z; h1[3] = (_Float16)t2.w;
                h1[4] = (_Float16)t3.x; h1[5] = (_Float16)t3.y; h1[6] = (_Float16)t3.z; h1[7] = (_Float16)t3.w;
                *(f16x8*)&Y[(size_t)grow * WC + gc0] = h0;
                *(f16x8*)&Y[(size_t)grow * WC + gc0 + 8] = h1;
            } else {
                int zc = gc0 - WC;
                f32x4 b0 = *(const f32x4*)&bias[zc + 0];
                f32x4 b1 = *(const f32x4*)&bias[zc + 4];
                f32x4 b2 = *(const f32x4*)&bias[zc + 8];
                f32x4 b3 = *(const f32x4*)&bias[zc + 12];
                t0 += b0; t1 += b1; t2 += b2; t3 += b3;
                *(f32x4*)&Z[(size_t)grow * WC + zc + 0] = t0;
                *(f32x4*)&Z[(size_t)grow * WC + zc + 4] = t1;
                *(f32x4*)&Z[(size_t)grow * WC + zc + 8] = t2;
                *(f32x4*)&Z[(size_t)grow * WC + zc + 12] = t3;
            }
        }
    }
}

// ---------------- Aggregation: h[n] = sum_e y16[esrc[e]] + z[n]; replicated col stats ----------------
template <int DIMS, int IT>
__global__ __launch_bounds__(256) void k_agg(
    const _Float16* __restrict__ y, const float* z, float* h,
    const uint* __restrict__ off, const uint* __restrict__ esrc,
    float* __restrict__ gstat, int N) {
    constexpr int TPN = DIMS / 8;
    constexpr int G = 256 / TPN;
    const int tid = threadIdx.x;
    const int c8 = tid & (TPN - 1);
    const int g = tid / TPN;
    const int col0 = c8 * 8;
    const int base = blockIdx.x * (G * IT);
    float ssum[8] = {0, 0, 0, 0, 0, 0, 0, 0};
    float ssq[8] = {0, 0, 0, 0, 0, 0, 0, 0};

    for (int it = 0; it < IT; ++it) {
        const int n = base + it * G + g;
        if (n < N) {
            const uint beg = off[n], end = off[n + 1];
            float acc[8] = {0, 0, 0, 0, 0, 0, 0, 0};
            uint e = beg;
            for (; e + 4 <= end; e += 4) {
                const uint s0 = esrc[e], s1 = esrc[e + 1];
                const uint s2 = esrc[e + 2], s3 = esrc[e + 3];
                const f16x8 a0 = *(const f16x8*)&y[(size_t)s0 * DIMS + col0];
                const f16x8 a1 = *(const f16x8*)&y[(size_t)s1 * DIMS + col0];
                const f16x8 a2 = *(const f16x8*)&y[(size_t)s2 * DIMS + col0];
                const f16x8 a3 = *(const f16x8*)&y[(size_t)s3 * DIMS + col0];
#pragma unroll
                for (int j = 0; j < 8; ++j)
                    acc[j] += ((float)a0[j] + (float)a1[j]) + ((float)a2[j] + (float)a3[j]);
            }
            for (; e < end; ++e) {
                const uint s0 = esrc[e];
                const f16x8 a0 = *(const f16x8*)&y[(size_t)s0 * DIMS + col0];
#pragma unroll
                for (int j = 0; j < 8; ++j) acc[j] += (float)a0[j];
            }
            const size_t idx = (size_t)n * DIMS + col0;
            f32x4 z0 = __builtin_nontemporal_load((const f32x4*)&z[idx]);
            f32x4 z1 = __builtin_nontemporal_load((const f32x4*)&z[idx + 4]);
            float hv[8];
            hv[0] = acc[0] + z0.x; hv[1] = acc[1] + z0.y; hv[2] = acc[2] + z0.z; hv[3] = acc[3] + z0.w;
            hv[4] = acc[4] + z1.x; hv[5] = acc[5] + z1.y; hv[6] = acc[6] + z1.z; hv[7] = acc[7] + z1.w;
            f32x4 h0 = {hv[0], hv[1], hv[2], hv[3]};
            f32x4 h1 = {hv[4], hv[5], hv[6], hv[7]};
            __builtin_nontemporal_store(h0, (f32x4*)&h[idx]);
            __builtin_nontemporal_store(h1, (f32x4*)&h[idx + 4]);
#pragma unroll
            for (int j = 0; j < 8; ++j) {
                ssum[j] += hv[j];
                ssq[j] += hv[j] * hv[j];
            }
        }
    }

    __shared__ f32x4 red[256][4];
    red[tid][0] = (f32x4){ssum[0], ssum[1], ssum[2], ssum[3]};
    red[tid][1] = (f32x4){ssum[4], ssum[5], ssum[6], ssum[7]};
    red[tid][2] = (f32x4){ssq[0], ssq[1], ssq[2], ssq[3]};
    red[tid][3] = (f32x4){ssq[4], ssq[5], ssq[6], ssq[7]};
    __syncthreads();
    for (int st = G / 2; st >= 1; st >>= 1) {
        if (g < st) {
#pragma unroll
            for (int q = 0; q < 4; ++q) red[tid][q] += red[tid + st * TPN][q];
        }
        __syncthreads();
    }
    if (g == 0) {
        float* gs = gstat + (blockIdx.x & (NREP - 1)) * (2 * DIMS);
        f32x4 s0 = red[c8][0], s1 = red[c8][1], q0 = red[c8][2], q1 = red[c8][3];
        unsafeAtomicAdd(&gs[col0 + 0], s0.x);
        unsafeAtomicAdd(&gs[col0 + 1], s0.y);
        unsafeAtomicAdd(&gs[col0 + 2], s0.z);
        unsafeAtomicAdd(&gs[col0 + 3], s0.w);
        unsafeAtomicAdd(&gs[col0 + 4], s1.x);
        unsafeAtomicAdd(&gs[col0 + 5], s1.y);
        unsafeAtomicAdd(&gs[col0 + 6], s1.z);
        unsafeAtomicAdd(&gs[col0 + 7], s1.w);
        unsafeAtomicAdd(&gs[DIMS + col0 + 0], q0.x);
        unsafeAtomicAdd(&gs[DIMS + col0 + 1], q0.y);
        unsafeAtomicAdd(&gs[DIMS + col0 + 2], q0.z);
        unsafeAtomicAdd(&gs[DIMS + col0 + 3], q0.w);
        unsafeAtomicAdd(&gs[DIMS + col0 + 4], q1.x);
        unsafeAtomicAdd(&gs[DIMS + col0 + 5], q1.y);
        unsafeAtomicAdd(&gs[DIMS + col0 + 6], q1.z);
        unsafeAtomicAdd(&gs[DIMS + col0 + 7], q1.w);
    }
}

// ---------------- finalize BN stats from NREP replicas ----------------
__global__ void k_finalize(const float* __restrict__ rep, float* __restrict__ mean,
                           float* __restrict__ inv, int C, float invN) {
    int c = threadIdx.x;
    if (c < C) {
        float s = 0.f, q = 0.f;
        for (int r = 0; r < NREP; ++r) {
            s += rep[r * 2 * C + c];
            q += rep[r * 2 * C + C + c];
        }
        float m = s * invN;
        float v = q * invN - m * m;
        mean[c] = m;
        inv[c] = rsqrtf(v + 1e-5f);
    }
}

// ---------------- final BN+relu elementwise ----------------
__global__ void k_out(const float* __restrict__ h2, const float* __restrict__ mean,
                      const float* __restrict__ inv, const float* __restrict__ gamma,
                      const float* __restrict__ beta, float* __restrict__ out, int nf4) {
    int i = blockIdx.x * blockDim.x + threadIdx.x;
    if (i < nf4) {
        int c = (i & 7) * 4;
        float4 h = ((const float4*)h2)[i];
        float4 m = *(const float4*)&mean[c];
        float4 iv = *(const float4*)&inv[c];
        float4 g = *(const float4*)&gamma[c];
        float4 b = *(const float4*)&beta[c];
        float4 o;
        o.x = frelu((h.x - m.x) * iv.x * g.x + b.x);
        o.y = frelu((h.y - m.y) * iv.y * g.y + b.y);
        o.z = frelu((h.z - m.z) * iv.z * g.z + b.z);
        o.w = frelu((h.w - m.w) * iv.w * g.w + b.w);
        ((float4*)out)[i] = o;
    }
}

extern "C" void kernel_launch(void* const* d_in, const int* in_sizes, int n_in,
                              void* d_out, int out_size, void* d_ws, size_t ws_size,
                              hipStream_t stream) {
    const float* x      = (const float*)d_in[0];
    const int*   eidx   = (const int*)d_in[1];
    const float* Wrel1  = (const float*)d_in[2];
    const float* brel1  = (const float*)d_in[3];
    const float* Wroot1 = (const float*)d_in[4];
    const float* gamma1 = (const float*)d_in[5];
    const float* beta1  = (const float*)d_in[6];
    const float* Wrel2  = (const float*)d_in[7];
    const float* brel2  = (const float*)d_in[8];
    const float* Wroot2 = (const float*)d_in[9];
    const float* gamma2 = (const float*)d_in[10];
    const float* beta2  = (const float*)d_in[11];

    const int N = in_sizes[0] / DIN;
    const int E = in_sizes[1] / 2;
    const int* src = eidx;
    const int* dst = eidx + E;
    const int nbuck = (N + BKT_NODES - 1) >> BKT_SHIFT;  // 196 for N=100000 (<=256)

    char* p = (char*)d_ws;
    auto alloc = [&](size_t bytes) {
        void* r = (void*)p;
        p += (bytes + 255) & ~(size_t)255;
        return r;
    };
    uint*      bcnt = (uint*)alloc(256 * 4);
    uint*      boff = (uint*)alloc(257 * 4);
    uint*      gcur = (uint*)alloc(256 * 4);
    uint*      gbuf = (uint*)alloc((size_t)E * 4);
    uint*      esrc = (uint*)alloc((size_t)E * 4);
    uint*      off  = (uint*)alloc((size_t)(N + 1) * 4);
    _Float16*  Bt1  = (_Float16*)alloc(256 * 128 * 2);
    _Float16*  Bt2  = (_Float16*)alloc(64 * 128 * 2);
    _Float16*  y1   = (_Float16*)alloc((size_t)N * DIN * 2);
    float*     z1   = (float*)alloc((size_t)N * DIN * 4);   // h1 aliases z1
    _Float16*  y2   = (_Float16*)alloc((size_t)N * DOUT * 2);
    float*     z2   = (float*)alloc((size_t)N * DOUT * 4);  // h2 aliases z2
    float*     stats = (float*)alloc((size_t)(NREP * 2 * DIN + NREP * 2 * DOUT + 2 * DIN + 2 * DOUT) * 4);
    float* s1rep = stats;
    float* s2rep = stats + NREP * 2 * DIN;
    float* mean1 = s2rep + NREP * 2 * DOUT;
    float* inv1  = mean1 + DIN;
    float* mean2 = inv1 + DIN;
    float* inv2  = mean2 + DOUT;

    const float invN = 1.f / (float)N;
    const int nstats = NREP * 2 * DIN + NREP * 2 * DOUT;
    const int nbE = (E + 8191) / 8192;
    const int nb64 = (N + 63) / 64;

    int nz = 256 + nstats;
    k_zero<<<(nz + 255) / 256, 256, 0, stream>>>(bcnt, 256, stats, nstats);
    k_bhist<<<nbE, 256, 0, stream>>>(dst, bcnt, E, nbuck);
    k_bscan<<<1, 256, 0, stream>>>(bcnt, boff, gcur, nbuck, E);
    k_part<<<nbE, 256, 0, stream>>>(src, dst, gcur, gbuf, E, nbuck);
    k_csr<<<nbuck, 256, 0, stream>>>(boff, gbuf, off, esrc, N, E, nbuck);
    k_prepw<<<320, 128, 0, stream>>>(Wrel1, Wroot1, Wrel2, Wroot2, Bt1, Bt2);

    // GEMM1: y1 (fp16) = x@Wrel1 ; z1 (fp32) = x@Wroot1 + brel1
    k_gemm<DIN, false><<<dim3(nb64, 4), 256, 0, stream>>>(
        x, Bt1, brel1, nullptr, nullptr, nullptr, nullptr, y1, z1, N);
    // agg1 + stats (h1 -> z1)
    k_agg<DIN, 2><<<(N + 31) / 32, 256, 0, stream>>>(y1, z1, z1, off, esrc, s1rep, N);
    k_finalize<<<1, DIN, 0, stream>>>(s1rep, mean1, inv1, DIN, invN);
    // GEMM2 with fused BN1+relu on A
    k_gemm<DOUT, true><<<dim3(nb64, 1), 256, 0, stream>>>(
        z1, Bt2, brel2, mean1, inv1, gamma1, beta1, y2, z2, N);
    // agg2 + stats (h2 -> z2)
    k_agg<DOUT, 1><<<(N + 63) / 64, 256, 0, stream>>>(y2, z2, z2, off, esrc, s2rep, N);
    k_finalize<<<1, 64, 0, stream>>>(s2rep, mean2, inv2, DOUT, invN);
    int nf4 = N * DOUT / 4;
    k_out<<<(nf4 + 255) / 256, 256, 0, stream>>>(z2, mean2, inv2, gamma2, beta2,
                                                 (float*)d_out, nf4);
}

// Round 5
// 324.628 us; speedup vs baseline: 3.3526x; 1.0769x over previous
//
#include <hip/hip_runtime.h>
#include <hip/hip_bf16.h>
#include <stdint.h>

#define DIN 128
#define DOUT 32
#define NREP 32
#define BKT_SHIFT 9
#define BKT_NODES 512
#define MAXBE 12288

typedef unsigned int uint;
typedef float f32x4 __attribute__((ext_vector_type(4)));
typedef _Float16 f16x8 __attribute__((ext_vector_type(8)));

__device__ __forceinline__ float frelu(float x) { return x > 0.f ? x : 0.f; }

// ---------------- K0: zero bucket counts + stat accumulators ----------------
__global__ void k_zero(uint* __restrict__ bcnt, int nb, float* __restrict__ stats, int nstats) {
    int i = blockIdx.x * blockDim.x + threadIdx.x;
    if (i < nb) bcnt[i] = 0u;
    else if (i < nb + nstats) stats[i - nb] = 0.f;
}

// ---------------- K1: bucket histogram (dst>>9), LDS-staged ----------------
__global__ __launch_bounds__(256) void k_bhist(const int* __restrict__ dst,
                                               uint* __restrict__ bcnt, int E, int nbuck) {
    __shared__ uint lh[256];
    const int t = threadIdx.x;
    lh[t] = 0;
    __syncthreads();
    const int base = blockIdx.x * 8192;
#pragma unroll 8
    for (int i = 0; i < 32; ++i) {
        int e = base + t + 256 * i;
        if (e < E) atomicAdd(&lh[((uint)dst[e]) >> BKT_SHIFT], 1u);
    }
    __syncthreads();
    if (t < nbuck && lh[t]) atomicAdd(&bcnt[t], lh[t]);
}

// ---------------- K2: scan bucket counts -> boff, gcur ----------------
__global__ __launch_bounds__(256) void k_bscan(const uint* __restrict__ bcnt,
                                               uint* __restrict__ boff, uint* __restrict__ gcur,
                                               int nbuck, int E) {
    __shared__ uint ps[256];
    const int t = threadIdx.x;
    uint v = (t < nbuck) ? bcnt[t] : 0u;
    ps[t] = v;
    __syncthreads();
    for (int o = 1; o < 256; o <<= 1) {
        uint u = (t >= o) ? ps[t - o] : 0u;
        __syncthreads();
        ps[t] += u;
        __syncthreads();
    }
    if (t < nbuck) {
        uint ex = ps[t] - v;
        boff[t] = ex;
        gcur[t] = ex;
    }
    if (t == 0) boff[nbuck] = (uint)E;
}

// ---------------- K3: partition edges into bucket-contiguous packed array ----------------
// gbuf[pos] = (dstLocal<<17) | src
__global__ __launch_bounds__(256) void k_part(const int* __restrict__ src,
                                              const int* __restrict__ dst,
                                              uint* __restrict__ gcur, uint* __restrict__ gbuf,
                                              int E, int nbuck) {
    __shared__ uint lh[256], lb[256], lc[256];
    const int t = threadIdx.x;
    lh[t] = 0;
    lc[t] = 0;
    __syncthreads();
    const int base = blockIdx.x * 8192;
#pragma unroll 8
    for (int i = 0; i < 32; ++i) {
        int e = base + t + 256 * i;
        if (e < E) atomicAdd(&lh[((uint)dst[e]) >> BKT_SHIFT], 1u);
    }
    __syncthreads();
    if (t < nbuck && lh[t]) lb[t] = atomicAdd(&gcur[t], lh[t]);
    __syncthreads();
#pragma unroll 8
    for (int i = 0; i < 32; ++i) {
        int e = base + t + 256 * i;
        if (e < E) {
            uint d = (uint)dst[e];
            uint s = (uint)src[e];
            uint b = d >> BKT_SHIFT;
            uint r = atomicAdd(&lc[b], 1u);
            gbuf[lb[b] + r] = ((d & (BKT_NODES - 1)) << 17) | s;
        }
    }
}

// ---------------- K4: per-bucket local CSR: off + esrc ----------------
__global__ __launch_bounds__(256) void k_csr(const uint* __restrict__ boff,
                                             const uint* __restrict__ gbuf,
                                             uint* __restrict__ off, uint* __restrict__ esrc,
                                             int N, int E, int nbuck) {
    __shared__ uint ed[MAXBE];
    __shared__ uint lh[BKT_NODES];
    __shared__ uint lsc[BKT_NODES];
    __shared__ uint ps[256];
    const int b = blockIdx.x, t = threadIdx.x;
    const uint bb = boff[b];
    int cnt = (int)(boff[b + 1] - bb);
    if (cnt > MAXBE) cnt = MAXBE;
    for (int i = t; i < cnt; i += 256) ed[i] = gbuf[bb + i];
    lh[t] = 0;
    lh[t + 256] = 0;
    __syncthreads();
    for (int i = t; i < cnt; i += 256) atomicAdd(&lh[ed[i] >> 17], 1u);
    __syncthreads();
    const uint v0 = lh[2 * t], v1 = lh[2 * t + 1];
    ps[t] = v0 + v1;
    __syncthreads();
    for (int o = 1; o < 256; o <<= 1) {
        uint u = (t >= o) ? ps[t - o] : 0u;
        __syncthreads();
        ps[t] += u;
        __syncthreads();
    }
    const uint ex = ps[t] - (v0 + v1);
    lsc[2 * t] = ex;
    lsc[2 * t + 1] = ex + v0;
    const int n0 = b << BKT_SHIFT;
    if (n0 + 2 * t < N) off[n0 + 2 * t] = bb + ex;
    if (n0 + 2 * t + 1 < N) off[n0 + 2 * t + 1] = bb + ex + v0;
    if (b == nbuck - 1 && t == 0) off[N] = (uint)E;
    __syncthreads();
    for (int i = t; i < cnt; i += 256) {
        uint p = ed[i];
        uint r = atomicAdd(&lsc[p >> 17], 1u);
        esrc[bb + r] = p & 0x1FFFFu;
    }
}

// ---------------- K5: transpose+convert weights to fp16 Bt[outcol][k] ----------------
__global__ void k_prepw(const float* __restrict__ Wrel1, const float* __restrict__ Wroot1,
                        const float* __restrict__ Wrel2, const float* __restrict__ Wroot2,
                        _Float16* __restrict__ Bt1, _Float16* __restrict__ Bt2) {
    const int c = blockIdx.x;
    const int k = threadIdx.x;
    if (c < 256) {
        const float* W = (c < 128) ? Wrel1 : Wroot1;
        int cl = c & 127;
        Bt1[c * 128 + k] = (_Float16)W[k * 128 + cl];
    } else {
        int c2 = c - 256;
        const float* W = (c2 < 32) ? Wrel2 : Wroot2;
        int cl = c2 & 31;
        Bt2[c2 * 128 + k] = (_Float16)W[k * 32 + cl];
    }
}

// ---------------- MFMA GEMM: [Y | Z] = A16 @ Bt^T ; Y,Z fp16 (Z += bias) ----------------
// AT = float (GEMM1) or _Float16 (GEMM2, with fused BN+relu on load).
template <int WC, bool NORM, typename AT>
__global__ __launch_bounds__(256) void k_gemm(
    const AT* __restrict__ A, const _Float16* __restrict__ Bt,
    const float* __restrict__ bias,
    const float* __restrict__ mean, const float* __restrict__ inv,
    const float* __restrict__ gamma, const float* __restrict__ beta,
    _Float16* __restrict__ Y, _Float16* __restrict__ Z, int N) {
    __shared__ __align__(16) char smem[32768];
    const int tid = threadIdx.x;
    const int rowBase = blockIdx.x * 64;
    const int colBase = blockIdx.y * 64;

    // stage A: -> LDS [64][128] fp16, byte ^= (row&7)<<4
    if constexpr (!NORM) {
        // fp32 A, no normalization
#pragma unroll
        for (int i = 0; i < 8; ++i) {
            int f = tid + 256 * i;
            int row = f >> 5, c4 = f & 31;
            int grow = rowBase + row;
            float4 v = make_float4(0.f, 0.f, 0.f, 0.f);
            if (grow < N) v = *(const float4*)&((const float*)A)[(size_t)grow * DIN + c4 * 4];
            union { short4 s; _Float16 h[4]; } u;
            u.h[0] = (_Float16)v.x; u.h[1] = (_Float16)v.y;
            u.h[2] = (_Float16)v.z; u.h[3] = (_Float16)v.w;
            int off = row * 256 + ((c4 * 8) ^ ((row & 7) << 4));
            *(short4*)(smem + off) = u.s;
        }
    } else {
        // fp16 A with BN+relu
#pragma unroll
        for (int i = 0; i < 4; ++i) {
            int f = tid + 256 * i;
            int row = f >> 4, sl = f & 15;
            int grow = rowBase + row;
            f16x8 hv = {};
            if (grow < N) {
                f16x8 a = *(const f16x8*)&((const _Float16*)A)[(size_t)grow * DIN + sl * 8];
                int k = sl * 8;
                f32x4 m0 = *(const f32x4*)&mean[k],  m1 = *(const f32x4*)&mean[k + 4];
                f32x4 i0 = *(const f32x4*)&inv[k],   i1 = *(const f32x4*)&inv[k + 4];
                f32x4 g0 = *(const f32x4*)&gamma[k], g1 = *(const f32x4*)&gamma[k + 4];
                f32x4 b0 = *(const f32x4*)&beta[k],  b1 = *(const f32x4*)&beta[k + 4];
#pragma unroll
                for (int j = 0; j < 4; ++j) {
                    float v = frelu(((float)a[j] - m0[j]) * i0[j] * g0[j] + b0[j]);
                    hv[j] = (_Float16)v;
                }
#pragma unroll
                for (int j = 0; j < 4; ++j) {
                    float v = frelu(((float)a[4 + j] - m1[j]) * i1[j] * g1[j] + b1[j]);
                    hv[4 + j] = (_Float16)v;
                }
            }
            int off = row * 256 + ((sl * 16) ^ ((row & 7) << 4));
            *(f16x8*)(smem + off) = hv;
        }
    }
    // stage B
#pragma unroll
    for (int i = 0; i < 4; ++i) {
        int f = tid + 256 * i;
        int row = f >> 4, sl = f & 15;
        f16x8 v = *(const f16x8*)&Bt[(size_t)(colBase + row) * 128 + sl * 8];
        int off = row * 256 + ((sl * 16) ^ ((row & 7) << 4));
        *(f16x8*)(smem + 16384 + off) = v;
    }
    __syncthreads();

    const int lane = tid & 63;
    const int w = tid >> 6;
    const int wrow = (w >> 1) * 32;
    const int wcol = (w & 1) * 32;
    const int lr = lane & 15;
    const int lk = lane >> 4;

    f32x4 acc[2][2] = {};
#pragma unroll
    for (int s = 0; s < 4; ++s) {
        f16x8 a[2], b[2];
#pragma unroll
        for (int m = 0; m < 2; ++m) {
            int row = wrow + m * 16 + lr;
            int off = row * 256 + (((s * 64) + lk * 16) ^ ((row & 7) << 4));
            a[m] = *(const f16x8*)(smem + off);
        }
#pragma unroll
        for (int n = 0; n < 2; ++n) {
            int col = wcol + n * 16 + lr;
            int off = col * 256 + (((s * 64) + lk * 16) ^ ((col & 7) << 4));
            b[n] = *(const f16x8*)(smem + 16384 + off);
        }
#pragma unroll
        for (int m = 0; m < 2; ++m)
#pragma unroll
            for (int n = 0; n < 2; ++n)
                acc[m][n] = __builtin_amdgcn_mfma_f32_16x16x32_f16(a[m], b[n], acc[m][n], 0, 0, 0);
    }

    __syncthreads();
    float* Cs = (float*)smem;
#pragma unroll
    for (int m = 0; m < 2; ++m)
#pragma unroll
        for (int n = 0; n < 2; ++n) {
            int r0 = wrow + m * 16 + (lane >> 4) * 4;
            int c = wcol + n * 16 + (lane & 15);
#pragma unroll
            for (int j = 0; j < 4; ++j) Cs[(r0 + j) * 68 + c] = acc[m][n][j];
        }
    __syncthreads();

    {
        int row = tid >> 2, cq = tid & 3;
        int grow = rowBase + row;
        if (grow < N) {
            const int cb = row * 68 + cq * 16;
            f32x4 t0 = *(const f32x4*)&Cs[cb + 0];
            f32x4 t1 = *(const f32x4*)&Cs[cb + 4];
            f32x4 t2 = *(const f32x4*)&Cs[cb + 8];
            f32x4 t3 = *(const f32x4*)&Cs[cb + 12];
            int gc0 = colBase + cq * 16;
            _Float16* dstp;
            int dcol;
            if (gc0 < WC) {
                dstp = Y; dcol = gc0;
            } else {
                dstp = Z; dcol = gc0 - WC;
                f32x4 b0 = *(const f32x4*)&bias[dcol + 0];
                f32x4 b1 = *(const f32x4*)&bias[dcol + 4];
                f32x4 b2 = *(const f32x4*)&bias[dcol + 8];
                f32x4 b3 = *(const f32x4*)&bias[dcol + 12];
                t0 += b0; t1 += b1; t2 += b2; t3 += b3;
            }
            f16x8 h0, h1;
            h0[0] = (_Float16)t0.x; h0[1] = (_Float16)t0.y; h0[2] = (_Float16)t0.z; h0[3] = (_Float16)t0.w;
            h0[4] = (_Float16)t1.x; h0[5] = (_Float16)t1.y; h0[6] = (_Float16)t1.z; h0[7] = (_Float16)t1.w;
            h1[0] = (_Float16)t2.x; h1[1] = (_Float16)t2.y; h1[2] = (_Float16)t2.z; h1[3] = (_Float16)t2.w;
            h1[4] = (_Float16)t3.x; h1[5] = (_Float16)t3.y; h1[6] = (_Float16)t3.z; h1[7] = (_Float16)t3.w;
            *(f16x8*)&dstp[(size_t)grow * WC + dcol] = h0;
            *(f16x8*)&dstp[(size_t)grow * WC + dcol + 8] = h1;
        }
    }
}

// ---------------- Aggregation: h[n] = sum_e y16[esrc[e]] + z[n]; replicated col stats ----------------
// y, z, h all fp16; stats in fp32. h may alias z.
template <int DIMS, int IT>
__global__ __launch_bounds__(256) void k_agg(
    const _Float16* __restrict__ y, const _Float16* z, _Float16* h,
    const uint* __restrict__ off, const uint* __restrict__ esrc,
    float* __restrict__ gstat, int N) {
    constexpr int TPN = DIMS / 8;
    constexpr int G = 256 / TPN;
    const int tid = threadIdx.x;
    const int c8 = tid & (TPN - 1);
    const int g = tid / TPN;
    const int col0 = c8 * 8;
    const int base = blockIdx.x * (G * IT);
    float ssum[8] = {0, 0, 0, 0, 0, 0, 0, 0};
    float ssq[8] = {0, 0, 0, 0, 0, 0, 0, 0};

    for (int it = 0; it < IT; ++it) {
        const int n = base + it * G + g;
        if (n < N) {
            const uint beg = off[n], end = off[n + 1];
            float acc[8] = {0, 0, 0, 0, 0, 0, 0, 0};
            uint e = beg;
            for (; e + 4 <= end; e += 4) {
                const uint s0 = esrc[e], s1 = esrc[e + 1];
                const uint s2 = esrc[e + 2], s3 = esrc[e + 3];
                const f16x8 a0 = *(const f16x8*)&y[(size_t)s0 * DIMS + col0];
                const f16x8 a1 = *(const f16x8*)&y[(size_t)s1 * DIMS + col0];
                const f16x8 a2 = *(const f16x8*)&y[(size_t)s2 * DIMS + col0];
                const f16x8 a3 = *(const f16x8*)&y[(size_t)s3 * DIMS + col0];
#pragma unroll
                for (int j = 0; j < 8; ++j)
                    acc[j] += ((float)a0[j] + (float)a1[j]) + ((float)a2[j] + (float)a3[j]);
            }
            for (; e < end; ++e) {
                const uint s0 = esrc[e];
                const f16x8 a0 = *(const f16x8*)&y[(size_t)s0 * DIMS + col0];
#pragma unroll
                for (int j = 0; j < 8; ++j) acc[j] += (float)a0[j];
            }
            const size_t idx = (size_t)n * DIMS + col0;
            const f16x8 zz = __builtin_nontemporal_load((const f16x8*)&z[idx]);
            float hv[8];
            f16x8 hs;
#pragma unroll
            for (int j = 0; j < 8; ++j) {
                hv[j] = acc[j] + (float)zz[j];
                hs[j] = (_Float16)hv[j];
            }
            __builtin_nontemporal_store(hs, (f16x8*)&h[idx]);
#pragma unroll
            for (int j = 0; j < 8; ++j) {
                ssum[j] += hv[j];
                ssq[j] += hv[j] * hv[j];
            }
        }
    }

    // conflict-free reduction: 4 separate [256] arrays, 16B/lane contiguous
    __shared__ f32x4 redA[256], redB[256], redC[256], redD[256];
    redA[tid] = (f32x4){ssum[0], ssum[1], ssum[2], ssum[3]};
    redB[tid] = (f32x4){ssum[4], ssum[5], ssum[6], ssum[7]};
    redC[tid] = (f32x4){ssq[0], ssq[1], ssq[2], ssq[3]};
    redD[tid] = (f32x4){ssq[4], ssq[5], ssq[6], ssq[7]};
    __syncthreads();
    for (int st = G / 2; st >= 1; st >>= 1) {
        if (g < st) {
            redA[tid] += redA[tid + st * TPN];
            redB[tid] += redB[tid + st * TPN];
            redC[tid] += redC[tid + st * TPN];
            redD[tid] += redD[tid + st * TPN];
        }
        __syncthreads();
    }
    if (g == 0) {
        float* gs = gstat + (blockIdx.x & (NREP - 1)) * (2 * DIMS);
        f32x4 s0 = redA[c8], s1 = redB[c8], q0 = redC[c8], q1 = redD[c8];
        unsafeAtomicAdd(&gs[col0 + 0], s0.x);
        unsafeAtomicAdd(&gs[col0 + 1], s0.y);
        unsafeAtomicAdd(&gs[col0 + 2], s0.z);
        unsafeAtomicAdd(&gs[col0 + 3], s0.w);
        unsafeAtomicAdd(&gs[col0 + 4], s1.x);
        unsafeAtomicAdd(&gs[col0 + 5], s1.y);
        unsafeAtomicAdd(&gs[col0 + 6], s1.z);
        unsafeAtomicAdd(&gs[col0 + 7], s1.w);
        unsafeAtomicAdd(&gs[DIMS + col0 + 0], q0.x);
        unsafeAtomicAdd(&gs[DIMS + col0 + 1], q0.y);
        unsafeAtomicAdd(&gs[DIMS + col0 + 2], q0.z);
        unsafeAtomicAdd(&gs[DIMS + col0 + 3], q0.w);
        unsafeAtomicAdd(&gs[DIMS + col0 + 4], q1.x);
        unsafeAtomicAdd(&gs[DIMS + col0 + 5], q1.y);
        unsafeAtomicAdd(&gs[DIMS + col0 + 6], q1.z);
        unsafeAtomicAdd(&gs[DIMS + col0 + 7], q1.w);
    }
}

// ---------------- finalize BN stats from NREP replicas ----------------
__global__ void k_finalize(const float* __restrict__ rep, float* __restrict__ mean,
                           float* __restrict__ inv, int C, float invN) {
    int c = threadIdx.x;
    if (c < C) {
        float s = 0.f, q = 0.f;
        for (int r = 0; r < NREP; ++r) {
            s += rep[r * 2 * C + c];
            q += rep[r * 2 * C + C + c];
        }
        float m = s * invN;
        float v = q * invN - m * m;
        mean[c] = m;
        inv[c] = rsqrtf(v + 1e-5f);
    }
}

// ---------------- final BN+relu elementwise (h2 fp16 -> out fp32) ----------------
__global__ void k_out(const _Float16* __restrict__ h2, const float* __restrict__ mean,
                      const float* __restrict__ inv, const float* __restrict__ gamma,
                      const float* __restrict__ beta, float* __restrict__ out, int nch) {
    int i = blockIdx.x * blockDim.x + threadIdx.x;
    if (i < nch) {
        int c = (i & 3) * 8;  // 32 cols = 4 chunks of 8
        f16x8 hv = *(const f16x8*)&h2[(size_t)i * 8];
        f32x4 m0 = *(const f32x4*)&mean[c],  m1 = *(const f32x4*)&mean[c + 4];
        f32x4 i0 = *(const f32x4*)&inv[c],   i1 = *(const f32x4*)&inv[c + 4];
        f32x4 g0 = *(const f32x4*)&gamma[c], g1 = *(const f32x4*)&gamma[c + 4];
        f32x4 b0 = *(const f32x4*)&beta[c],  b1 = *(const f32x4*)&beta[c + 4];
        f32x4 o0, o1;
#pragma unroll
        for (int j = 0; j < 4; ++j) o0[j] = frelu(((float)hv[j] - m0[j]) * i0[j] * g0[j] + b0[j]);
#pragma unroll
        for (int j = 0; j < 4; ++j) o1[j] = frelu(((float)hv[4 + j] - m1[j]) * i1[j] * g1[j] + b1[j]);
        *(f32x4*)&out[(size_t)i * 8] = o0;
        *(f32x4*)&out[(size_t)i * 8 + 4] = o1;
    }
}

extern "C" void kernel_launch(void* const* d_in, const int* in_sizes, int n_in,
                              void* d_out, int out_size, void* d_ws, size_t ws_size,
                              hipStream_t stream) {
    const float* x      = (const float*)d_in[0];
    const int*   eidx   = (const int*)d_in[1];
    const float* Wrel1  = (const float*)d_in[2];
    const float* brel1  = (const float*)d_in[3];
    const float* Wroot1 = (const float*)d_in[4];
    const float* gamma1 = (const float*)d_in[5];
    const float* beta1  = (const float*)d_in[6];
    const float* Wrel2  = (const float*)d_in[7];
    const float* brel2  = (const float*)d_in[8];
    const float* Wroot2 = (const float*)d_in[9];
    const float* gamma2 = (const float*)d_in[10];
    const float* beta2  = (const float*)d_in[11];

    const int N = in_sizes[0] / DIN;
    const int E = in_sizes[1] / 2;
    const int* src = eidx;
    const int* dst = eidx + E;
    const int nbuck = (N + BKT_NODES - 1) >> BKT_SHIFT;

    char* p = (char*)d_ws;
    auto alloc = [&](size_t bytes) {
        void* r = (void*)p;
        p += (bytes + 255) & ~(size_t)255;
        return r;
    };
    uint*      bcnt = (uint*)alloc(256 * 4);
    uint*      boff = (uint*)alloc(257 * 4);
    uint*      gcur = (uint*)alloc(256 * 4);
    uint*      gbuf = (uint*)alloc((size_t)E * 4);
    uint*      esrc = (uint*)alloc((size_t)E * 4);
    uint*      off  = (uint*)alloc((size_t)(N + 1) * 4);
    _Float16*  Bt1  = (_Float16*)alloc(256 * 128 * 2);
    _Float16*  Bt2  = (_Float16*)alloc(64 * 128 * 2);
    _Float16*  y1   = (_Float16*)alloc((size_t)N * DIN * 2);
    _Float16*  z1   = (_Float16*)alloc((size_t)N * DIN * 2);   // h1 aliases z1
    _Float16*  y2   = (_Float16*)alloc((size_t)N * DOUT * 2);
    _Float16*  z2   = (_Float16*)alloc((size_t)N * DOUT * 2);  // h2 aliases z2
    float*     stats = (float*)alloc((size_t)(NREP * 2 * DIN + NREP * 2 * DOUT + 2 * DIN + 2 * DOUT) * 4);
    float* s1rep = stats;
    float* s2rep = stats + NREP * 2 * DIN;
    float* mean1 = s2rep + NREP * 2 * DOUT;
    float* inv1  = mean1 + DIN;
    float* mean2 = inv1 + DIN;
    float* inv2  = mean2 + DOUT;

    const float invN = 1.f / (float)N;
    const int nstats = NREP * 2 * DIN + NREP * 2 * DOUT;
    const int nbE = (E + 8191) / 8192;
    const int nb64 = (N + 63) / 64;

    int nz = 256 + nstats;
    k_zero<<<(nz + 255) / 256, 256, 0, stream>>>(bcnt, 256, stats, nstats);
    k_bhist<<<nbE, 256, 0, stream>>>(dst, bcnt, E, nbuck);
    k_bscan<<<1, 256, 0, stream>>>(bcnt, boff, gcur, nbuck, E);
    k_part<<<nbE, 256, 0, stream>>>(src, dst, gcur, gbuf, E, nbuck);
    k_csr<<<nbuck, 256, 0, stream>>>(boff, gbuf, off, esrc, N, E, nbuck);
    k_prepw<<<320, 128, 0, stream>>>(Wrel1, Wroot1, Wrel2, Wroot2, Bt1, Bt2);

    // GEMM1: y1 = x@Wrel1 ; z1 = x@Wroot1 + brel1 (both fp16)
    k_gemm<DIN, false, float><<<dim3(nb64, 4), 256, 0, stream>>>(
        x, Bt1, brel1, nullptr, nullptr, nullptr, nullptr, y1, z1, N);
    // agg1 + stats (h1 -> z1)
    k_agg<DIN, 2><<<(N + 31) / 32, 256, 0, stream>>>(y1, z1, z1, off, esrc, s1rep, N);
    k_finalize<<<1, DIN, 0, stream>>>(s1rep, mean1, inv1, DIN, invN);
    // GEMM2 with fused BN1+relu on fp16 A
    k_gemm<DOUT, true, _Float16><<<dim3(nb64, 1), 256, 0, stream>>>(
        z1, Bt2, brel2, mean1, inv1, gamma1, beta1, y2, z2, N);
    // agg2 + stats (h2 -> z2)
    k_agg<DOUT, 1><<<(N + 63) / 64, 256, 0, stream>>>(y2, z2, z2, off, esrc, s2rep, N);
    k_finalize<<<1, 64, 0, stream>>>(s2rep, mean2, inv2, DOUT, invN);
    int nch = N * DOUT / 8;
    k_out<<<(nch + 255) / 256, 256, 0, stream>>>(z2, mean2, inv2, gamma2, beta2,
                                                 (float*)d_out, nch);
}